// Round 2
// baseline (410.789 us; speedup 1.0000x reference)
//
#include <hip/hip_runtime.h>
#include <cstdint>
#include <cstddef>

typedef unsigned int u32;
typedef unsigned short u16;
typedef __attribute__((ext_vector_type(8))) short bf16x8;   // 8 bf16 = 4 VGPR
typedef __attribute__((ext_vector_type(4))) float f32x4;

#define DEV __device__ __forceinline__

DEV float b2f(u16 u){ return __uint_as_float(((u32)u)<<16); }
DEV u16 f2b(float f){ u32 x = __float_as_uint(f); x += 0x7fffu + ((x>>16)&1u); return (u16)(x>>16); }
DEV u32 pk2(float a, float b){
  u32 r;
  asm("v_cvt_pk_bf16_f32 %0, %1, %2" : "=v"(r) : "v"(a), "v"(b));
  return r;
}

DEV void gll16(const void* g, void* l){
  __builtin_amdgcn_global_load_lds((const __attribute__((address_space(1))) u32*)g,
                                   (__attribute__((address_space(3))) u32*)l, 16, 0, 0);
}

// token row -> (window, in-window index);  H=W=D=32, g=8
DEV void win_n(int r, int& win, int& n){
  int d_ = r & 31, w_ = (r>>5)&31, h_ = r>>10;
  win = ((h_>>3)<<4) | ((w_>>3)<<2) | (d_>>3);
  n   = ((h_&7)<<6)  | ((w_&7)<<3)  | (d_&7);
}
// window-order row -> token row
DEV int tok_of(int r){
  int win = r>>9, nn = r&511;
  int bh = win>>4, bw=(win>>2)&3, bd=win&3;
  int ih = nn>>6,  iw=(nn>>3)&7,  id=nn&7;
  return ((bh*8+ih)<<10) | ((bw*8+iw)<<5) | (bd*8+id);
}

// ---------------- small prep kernels ----------------

// dst bf16 [N][K] = transpose(src fp32 [K][N])
__global__ void wtr_k(const float* __restrict__ w, u16* __restrict__ wt, int K, int N){
  int f = blockIdx.x*256 + threadIdx.x;
  if (f >= K*N) return;
  int n = f / K, k = f - n*K;
  wt[f] = f2b(w[(size_t)k*N + n]);
}

__global__ void conv_k(const float* __restrict__ x, u16* __restrict__ o, int n4){
  int stride = gridDim.x*blockDim.x;
  for (int i = blockIdx.x*blockDim.x + threadIdx.x; i < n4; i += stride){
    const float4 v = *(const float4*)(x + (size_t)i*4);
    u32 lo = (u32)f2b(v.x) | ((u32)f2b(v.y)<<16);
    u32 hi = (u32)f2b(v.z) | ((u32)f2b(v.w)<<16);
    *(uint2*)(o + (size_t)i*4) = make_uint2(lo, hi);
  }
}

// LayerNorm over 256 cols, one wave per row, writes bf16
__global__ __launch_bounds__(256)
void ln_k(const float* __restrict__ x, const float* __restrict__ g,
          const float* __restrict__ b, u16* __restrict__ out){
  int row  = blockIdx.x*4 + (threadIdx.x>>6);
  int lane = threadIdx.x & 63;
  const float4 v = *(const float4*)(x + (size_t)row*256 + lane*4);
  float s = v.x+v.y+v.z+v.w;
  #pragma unroll
  for (int m=1;m<64;m<<=1) s += __shfl_xor(s, m);
  float mean = s * (1.0f/256.0f);
  float d0=v.x-mean,d1=v.y-mean,d2=v.z-mean,d3=v.w-mean;
  float q = d0*d0+d1*d1+d2*d2+d3*d3;
  #pragma unroll
  for (int m=1;m<64;m<<=1) q += __shfl_xor(q, m);
  float rs = rsqrtf(q*(1.0f/256.0f) + 1e-5f);
  const float4 gg = *(const float4*)(g + lane*4);
  const float4 bb = *(const float4*)(b + lane*4);
  u32 lo = (u32)f2b(d0*rs*gg.x+bb.x) | ((u32)f2b(d1*rs*gg.y+bb.y)<<16);
  u32 hi = (u32)f2b(d2*rs*gg.z+bb.z) | ((u32)f2b(d3*rs*gg.w+bb.w)<<16);
  *(uint2*)(out + (size_t)row*256 + lane*4) = make_uint2(lo,hi);
}

// position-bias MLP: one thread per table row (3375 rows)
template<int NOUT>
DEV void pstage(float* v, const float* g, const float* b, const float* W, const float* bb){
  float m = 0.f;
  #pragma unroll
  for (int i=0;i<16;i++) m += v[i];
  m *= 0.0625f;
  float q = 0.f;
  #pragma unroll
  for (int i=0;i<16;i++){ float d=v[i]-m; q += d*d; }
  float rs = rsqrtf(q*0.0625f + 1e-5f);
  float u[16];
  #pragma unroll
  for (int i=0;i<16;i++){ float t = (v[i]-m)*rs*g[i] + b[i]; u[i] = t>0.f?t:0.f; }
  #pragma unroll
  for (int o=0;o<NOUT;o++){
    float s = bb[o];
    #pragma unroll
    for (int kk=0;kk<16;kk++) s += u[kk]*W[kk*NOUT+o];
    v[o] = s;
  }
}

__global__ void posmlp_k(const float* pp_w, const float* pp_b,
                         const float* g1, const float* b1, const float* w1, const float* bb1,
                         const float* g2, const float* b2, const float* w2, const float* bb2,
                         const float* g3, const float* b3, const float* w3, const float* bb3,
                         float* __restrict__ pos){
  int i = blockIdx.x*256 + threadIdx.x;
  if (i >= 3375) return;
  int t = i;
  int bd = t % 15; t /= 15;
  int bw = t % 15; t /= 15;
  int bh = t;
  float fh = (float)(bh-7), fw = (float)(bw-7), fd = (float)(bd-7);
  float v[16];
  #pragma unroll
  for (int o=0;o<16;o++) v[o] = fh*pp_w[o] + fw*pp_w[16+o] + fd*pp_w[32+o] + pp_b[o];
  pstage<16>(v, g1,b1,w1,bb1);
  pstage<16>(v, g2,b2,w2,bb2);
  pstage<8> (v, g3,b3,w3,bb3);
  #pragma unroll
  for (int h=0;h<8;h++) pos[(size_t)i*8 + h] = v[h];
}

// expand bias into S^T MFMA-fragment layout:
// biasF[h][qc(32)][nc(32)][lane(64)][j(4)] = bias[q=qc*16+(lane&15)][n=nc*16+(lane>>4)*4+j]
__global__ void biasx_k(const float* __restrict__ pos, u16* __restrict__ biasF){
  int f = blockIdx.x*256 + threadIdx.x;    // 2,097,152 total
  int j = f&3, ln = (f>>2)&63, nc = (f>>8)&31, qc = (f>>13)&31, h = f>>18;
  int q = qc*16 + (ln&15);
  int k = nc*16 + ((ln>>4)<<2) + j;
  int rh = (q>>6) - (k>>6) + 7;
  int rw = ((q>>3)&7) - ((k>>3)&7) + 7;
  int rd = (q&7) - (k&7) + 7;
  int idx = (rh*15 + rw)*15 + rd;
  biasF[f] = f2b(pos[idx*8 + h]);
}

// ---------------- GEMM: C[M][·] = A[M][K](bf16) @ Bt[N][K](bf16)^T, per-mode epilogue ----------------
struct GemmP {
  const u16* A; const u16* Bt;
  int K;
  const float* bvec;
  float scale;
  const float* add32;
  float* out32;
  u16* out16;
  u16* out16b;
};

template<int MODE>
__global__ __launch_bounds__(256)
void gemm_k(GemmP p){
  __shared__ u16 lA[2][4096];
  __shared__ u16 lB[2][4096];
  const int tid = threadIdx.x;
  const int wid = tid>>6, lane = tid&63;
  const int lr = lane&15, lg = lane>>4;
  const int m0 = blockIdx.x*128, n0 = blockIdx.y*128;
  const int K = p.K;
  const int nt = K>>5;
  const int wm = (wid>>1)*64, wn = (wid&1)*64;
  const f32x4 z4 = {0.f,0.f,0.f,0.f};

  f32x4 acc[4][4];
  #pragma unroll
  for (int i=0;i<4;i++)
    #pragma unroll
    for (int j=0;j<4;j++) acc[i][j] = z4;

  // prologue stage (t = 0)
  #pragma unroll
  for (int r=0;r<2;r++){
    int off = (r*256 + tid)*16;
    int row = off>>6, kc = (off&63)>>1;
    gll16(p.A  + (size_t)(m0+row)*K + kc, (char*)lA[0] + off);
    gll16(p.Bt + (size_t)(n0+row)*K + kc, (char*)lB[0] + off);
  }
  __syncthreads();
  int cur = 0;
  for (int t=0; t<nt; ++t){
    if (t+1 < nt){
      int k0 = (t+1)<<5;
      #pragma unroll
      for (int r=0;r<2;r++){
        int off = (r*256 + tid)*16;
        int row = off>>6, kc = (off&63)>>1;
        gll16(p.A  + (size_t)(m0+row)*K + k0 + kc, (char*)lA[cur^1] + off);
        gll16(p.Bt + (size_t)(n0+row)*K + k0 + kc, (char*)lB[cur^1] + off);
      }
    }
    bf16x8 af[4], bfr[4];
    #pragma unroll
    for (int i=0;i<4;i++){
      af[i]  = *(const bf16x8*)&lA[cur][(wm + i*16 + lr)*32 + lg*8];
      bfr[i] = *(const bf16x8*)&lB[cur][(wn + i*16 + lr)*32 + lg*8];
    }
    #pragma unroll
    for (int i=0;i<4;i++)
      #pragma unroll
      for (int j=0;j<4;j++)
        acc[i][j] = __builtin_amdgcn_mfma_f32_16x16x32_bf16(af[i], bfr[j], acc[i][j], 0,0,0);
    __syncthreads();
    cur ^= 1;
  }

  // epilogue: D layout col=lane&15, row=(lane>>4)*4+v  [verified m89]
  #pragma unroll
  for (int i=0;i<4;i++){
    #pragma unroll
    for (int j=0;j<4;j++){
      #pragma unroll
      for (int v=0;v<4;v++){
        int r = m0 + wm + i*16 + lg*4 + v;
        int c = n0 + wn + j*16 + lr;
        float val = acc[i][j][v];
        if constexpr (MODE==0){           // Q: (val+b)*scale -> Q[win*8+h][n][d]
          float qv = (val + p.bvec[c]) * p.scale;
          int win, n; win_n(r, win, n);
          int hh = c>>5, dd = c&31;
          p.out16[((size_t)((win*8+hh)*512 + n)<<5) + dd] = f2b(qv);
        } else if constexpr (MODE==1){    // K (c<256) / V (c>=256), MFMA fragment layout
          float ov = val + p.bvec[c];
          int win, n; win_n(r, win, n);
          int cc = c & 255;
          int hh = cc>>5, dd = cc&31;
          size_t base = (size_t)(win*8+hh)*16384;
          if (c < 256){
            // K frag: [nc][lane][8] : K[n=nc*16+(ln&15)][d=(ln>>4)*8+j]
            int nc = n>>4, ln2 = ((dd>>3)<<4)|(n&15), jj = dd&7;
            p.out16[base + (size_t)(nc*64+ln2)*8 + jj] = f2b(ov);
          } else {
            // V frag: [kc*2+dblk][lane][8] : V[n=kc*32+(ln>>4)*8+j][d=dblk*16+(ln&15)]
            int fi = ((n>>5)<<1) | (dd>>4);
            int ln2 = (((n>>3)&3)<<4)|(dd&15), jj = n&7;
            p.out16b[base + (size_t)(fi*64+ln2)*8 + jj] = f2b(ov);
          }
        } else if constexpr (MODE==2){    // proj + x residual, window row -> token row
          int l = tok_of(r);
          size_t o = (size_t)l*256 + c;
          p.out32[o] = val + p.bvec[c] + p.add32[o];
        } else if constexpr (MODE==3){    // fc1 + exact GELU
          float u = val + p.bvec[c];
          float ge = 0.5f*u*(1.0f + erff(u*0.70710678118654752f));
          p.out16[(size_t)r*1024 + c] = f2b(ge);
        } else {                          // fc2 + residual -> fp32 out
          size_t o = (size_t)r*256 + c;
          p.out32[o] = val + p.bvec[c] + p.add32[o];
        }
      }
    }
  }
}

// ---------------- attention: one block per (window, head) ----------------
// S^T = mfma(Kfrag, Qfrag): lane owns one q-row; softmax lane-local;
// P -> A-frag via cvt_pk + permlane32/16 swaps; all LDS reads wave-contiguous.
__global__ __launch_bounds__(256)
void attn_k(const u16* __restrict__ Q, const u16* __restrict__ Kf,
            const u16* __restrict__ Vf, const u16* __restrict__ biasF,
            u16* __restrict__ out){
  __shared__ u16 lK[16384];      // 32 frags x 1KB, fragment order
  __shared__ u16 lV[16384];      // 32 frags x 1KB (16 kc x 2 dblk)
  const int bid = blockIdx.x;
  const int win = bid>>3, hh = bid&7;
  const int tid = threadIdx.x, wid = tid>>6, lane = tid&63;
  const int lr = lane&15, lg = lane>>4;
  const u16* Kb = Kf + (size_t)bid*16384;
  const u16* Vb = Vf + (size_t)bid*16384;
  const u16* Qb = Q  + (size_t)bid*16384;
  #pragma unroll
  for (int r=0;r<8;r++){
    int off = (r*256 + tid)*16;
    gll16((const char*)Kb + off, (char*)lK + off);
    gll16((const char*)Vb + off, (char*)lV + off);
  }
  __syncthreads();
  const u16* bF = biasF + ((size_t)hh<<18);
  const f32x4 z4 = {0.f,0.f,0.f,0.f};

  for (int ch=0; ch<8; ++ch){
    const int r0 = wid*128 + ch*16;
    const int qc = r0>>4;
    // Q fragment straight from global (covers one contiguous 1KB chunk per wave)
    bf16x8 qf = *(const bf16x8*)(Qb + (size_t)(r0+lr)*32 + lg*8);
    // S^T frags: sf[nc][v] = S[q=r0+lr][n=nc*16+lg*4+v]
    f32x4 sf[32];
    #pragma unroll
    for (int nc=0;nc<32;nc++){
      bf16x8 kf = *(const bf16x8*)&lK[(nc*64 + lane)*8];
      sf[nc] = __builtin_amdgcn_mfma_f32_16x16x32_bf16(kf, qf, z4, 0,0,0);
    }
    // + bias (fragment-layout table, 8B coalesced per lane)
    const u16* bq = bF + ((size_t)qc<<13) + lane*4;
    #pragma unroll
    for (int nc=0;nc<32;nc++){
      uint2 bv = *(const uint2*)(bq + nc*256);
      sf[nc][0] += b2f((u16)(bv.x & 0xffffu));
      sf[nc][1] += b2f((u16)(bv.x >> 16));
      sf[nc][2] += b2f((u16)(bv.y & 0xffffu));
      sf[nc][3] += b2f((u16)(bv.y >> 16));
    }
    // softmax: each lane owns full row q=r0+lr (128 vals); partner lanes differ in bits 4,5
    float m = -3.0e38f;
    #pragma unroll
    for (int nc=0;nc<32;nc++)
      m = fmaxf(m, fmaxf(fmaxf(sf[nc][0],sf[nc][1]), fmaxf(sf[nc][2],sf[nc][3])));
    m = fmaxf(m, __shfl_xor(m,16));
    m = fmaxf(m, __shfl_xor(m,32));
    float s = 0.f;
    #pragma unroll
    for (int nc=0;nc<32;nc++){
      #pragma unroll
      for (int v=0;v<4;v++){ float e = __expf(sf[nc][v]-m); sf[nc][v]=e; s+=e; }
    }
    s += __shfl_xor(s,16);
    s += __shfl_xor(s,32);
    // PV: assemble P A-frags in-register (cvt_pk + permlane swaps), MFMA against V frags
    f32x4 o0 = z4, o1 = z4;
    #pragma unroll
    for (int kc=0;kc<16;kc++){
      u32 a0 = pk2(sf[2*kc  ][0], sf[2*kc  ][1]);
      u32 a1 = pk2(sf[2*kc  ][2], sf[2*kc  ][3]);
      u32 b0 = pk2(sf[2*kc+1][0], sf[2*kc+1][1]);
      u32 b1 = pk2(sf[2*kc+1][2], sf[2*kc+1][3]);
      asm("v_permlane32_swap_b32 %0, %1" : "+v"(a0), "+v"(b0));
      asm("v_permlane16_swap_b32 %0, %1" : "+v"(a0), "+v"(b0));  // a0=T0, b0=T2
      asm("v_permlane32_swap_b32 %0, %1" : "+v"(a1), "+v"(b1));
      asm("v_permlane16_swap_b32 %0, %1" : "+v"(a1), "+v"(b1));  // a1=T1, b1=T3
      bf16x8 pf;
      ((u32*)&pf)[0]=a0; ((u32*)&pf)[1]=a1; ((u32*)&pf)[2]=b0; ((u32*)&pf)[3]=b1;
      bf16x8 v0 = *(const bf16x8*)&lV[(size_t)((kc*2+0)*64 + lane)*8];
      bf16x8 v1 = *(const bf16x8*)&lV[(size_t)((kc*2+1)*64 + lane)*8];
      o0 = __builtin_amdgcn_mfma_f32_16x16x32_bf16(pf, v0, o0, 0,0,0);
      o1 = __builtin_amdgcn_mfma_f32_16x16x32_bf16(pf, v1, o1, 0,0,0);
    }
    #pragma unroll
    for (int v=0;v<4;v++){
      float inv = 1.0f / __shfl(s, lg*4+v);
      int n = r0 + lg*4 + v;
      size_t base = ((size_t)(win*512 + n))*256 + hh*32;
      out[base + lr]      = f2b(o0[v]*inv);
      out[base + 16 + lr] = f2b(o1[v]*inv);
    }
  }
}

// ---------------- host launch ----------------
extern "C" void kernel_launch(void* const* d_in, const int* in_sizes, int n_in,
                              void* d_out, int out_size, void* d_ws, size_t ws_size,
                              hipStream_t stream){
  const float* x      = (const float*)d_in[0];
  const float* y      = (const float*)d_in[1];
  const float* n1_g   = (const float*)d_in[2];
  const float* n1_b   = (const float*)d_in[3];
  const float* qkv_w  = (const float*)d_in[4];
  const float* qkv_b  = (const float*)d_in[5];
  const float* pp_w   = (const float*)d_in[6];
  const float* pp_b   = (const float*)d_in[7];
  const float* p1_lng = (const float*)d_in[8];
  const float* p1_lnb = (const float*)d_in[9];
  const float* p1_w   = (const float*)d_in[10];
  const float* p1_b   = (const float*)d_in[11];
  const float* p2_lng = (const float*)d_in[12];
  const float* p2_lnb = (const float*)d_in[13];
  const float* p2_w   = (const float*)d_in[14];
  const float* p2_b   = (const float*)d_in[15];
  const float* p3_lng = (const float*)d_in[16];
  const float* p3_lnb = (const float*)d_in[17];
  const float* p3_w   = (const float*)d_in[18];
  const float* p3_b   = (const float*)d_in[19];
  const float* proj_w = (const float*)d_in[20];
  const float* proj_b = (const float*)d_in[21];
  const float* n2_g   = (const float*)d_in[22];
  const float* n2_b   = (const float*)d_in[23];
  const float* fc1_w  = (const float*)d_in[24];
  const float* fc1_b  = (const float*)d_in[25];
  const float* fc2_w  = (const float*)d_in[26];
  const float* fc2_b  = (const float*)d_in[27];
  float* out = (float*)d_out;
  char* ws = (char*)d_ws;

  // workspace layout (bytes)
  u16*   qkvT  = (u16*)  (ws + 0);          // [768][256] bf16
  u16*   projT = (u16*)  (ws + 393216);     // [256][256]
  u16*   fc1T  = (u16*)  (ws + 524288);     // [1024][256]
  u16*   fc2T  = (u16*)  (ws + 1048576);    // [256][1024]
  float* pos   = (float*)(ws + 1572864);    // [3375][8] fp32
  u16*   biasF = (u16*)  (ws + 1703936);    // 2,097,152 bf16
  u16*   xn    = (u16*)  (ws + 5898240);    // [32768][256]
  u16*   yb    = (u16*)  (ws + 22675456);
  u16*   Qb    = (u16*)  (ws + 39452672);   // [512 bh][512 n][32 d]
  u16*   Kfb   = (u16*)  (ws + 56229888);   // [512 bh][32 frag][64 lane][8]
  u16*   Vfb   = (u16*)  (ws + 73007104);   // [512 bh][32 frag][64 lane][8]
  u16*   attn  = (u16*)  (ws + 89784320);   // [32768][256] window-row order
  float* xres  = (float*)(ws + 106561536);  // [32768][256] fp32   (end 140,115,968)
  u16*   hbuf  = xn;     // alias: MLP hidden [32768][1024], xn/yb/Qb dead by then
  u16*   x2n   = attn;   // alias: LN2 output, attn dead after proj

  wtr_k<<<768, 256,0,stream>>>(qkv_w, qkvT, 256, 768);
  wtr_k<<<256, 256,0,stream>>>(proj_w, projT, 256, 256);
  wtr_k<<<1024,256,0,stream>>>(fc1_w, fc1T, 256, 1024);
  wtr_k<<<1024,256,0,stream>>>(fc2_w, fc2T, 1024, 256);
  posmlp_k<<<14,256,0,stream>>>(pp_w, pp_b,
                                p1_lng,p1_lnb,p1_w,p1_b,
                                p2_lng,p2_lnb,p2_w,p2_b,
                                p3_lng,p3_lnb,p3_w,p3_b, pos);
  biasx_k<<<8192,256,0,stream>>>(pos, biasF);
  ln_k<<<8192,256,0,stream>>>(x, n1_g, n1_b, xn);
  conv_k<<<2048,256,0,stream>>>(y, yb, 2097152);

  GemmP pq; pq.A=xn; pq.Bt=qkvT; pq.K=256; pq.bvec=qkv_b;
  pq.scale=0.17677669529663687f; pq.add32=nullptr; pq.out32=nullptr; pq.out16=Qb; pq.out16b=nullptr;
  gemm_k<0><<<dim3(256,2),256,0,stream>>>(pq);

  GemmP pkv; pkv.A=yb; pkv.Bt=qkvT + 256*256; pkv.K=256; pkv.bvec=qkv_b + 256;
  pkv.scale=1.f; pkv.add32=nullptr; pkv.out32=nullptr; pkv.out16=Kfb; pkv.out16b=Vfb;
  gemm_k<1><<<dim3(256,4),256,0,stream>>>(pkv);

  attn_k<<<512,256,0,stream>>>(Qb, Kfb, Vfb, biasF, attn);

  GemmP pp; pp.A=attn; pp.Bt=projT; pp.K=256; pp.bvec=proj_b;
  pp.scale=1.f; pp.add32=x; pp.out32=xres; pp.out16=nullptr; pp.out16b=nullptr;
  gemm_k<2><<<dim3(256,2),256,0,stream>>>(pp);

  ln_k<<<8192,256,0,stream>>>(xres, n2_g, n2_b, x2n);

  GemmP pf1; pf1.A=x2n; pf1.Bt=fc1T; pf1.K=256; pf1.bvec=fc1_b;
  pf1.scale=1.f; pf1.add32=nullptr; pf1.out32=nullptr; pf1.out16=hbuf; pf1.out16b=nullptr;
  gemm_k<3><<<dim3(256,8),256,0,stream>>>(pf1);

  GemmP pf2; pf2.A=hbuf; pf2.Bt=fc2T; pf2.K=1024; pf2.bvec=fc2_b;
  pf2.scale=1.f; pf2.add32=xres; pf2.out32=out; pf2.out16=nullptr; pf2.out16b=nullptr;
  gemm_k<4><<<dim3(256,2),256,0,stream>>>(pf2);
}

// Round 3
// 344.873 us; speedup vs baseline: 1.1911x; 1.1911x over previous
//
#include <hip/hip_runtime.h>
#include <cstdint>
#include <cstddef>

typedef unsigned int u32;
typedef unsigned short u16;
typedef __attribute__((ext_vector_type(8))) short bf16x8;   // 8 bf16 = 4 VGPR
typedef __attribute__((ext_vector_type(4))) float f32x4;

#define DEV __device__ __forceinline__

DEV float b2f(u16 u){ return __uint_as_float(((u32)u)<<16); }
DEV u16 f2b(float f){ u32 x = __float_as_uint(f); x += 0x7fffu + ((x>>16)&1u); return (u16)(x>>16); }
DEV u32 pk2(float a, float b){
  u32 r;
  asm("v_cvt_pk_bf16_f32 %0, %1, %2" : "=v"(r) : "v"(a), "v"(b));
  return r;
}

DEV void gll16(const void* g, void* l){
  __builtin_amdgcn_global_load_lds((const __attribute__((address_space(1))) u32*)g,
                                   (__attribute__((address_space(3))) u32*)l, 16, 0, 0);
}

// token row -> (window, in-window index);  H=W=D=32, g=8
DEV void win_n(int r, int& win, int& n){
  int d_ = r & 31, w_ = (r>>5)&31, h_ = r>>10;
  win = ((h_>>3)<<4) | ((w_>>3)<<2) | (d_>>3);
  n   = ((h_&7)<<6)  | ((w_&7)<<3)  | (d_&7);
}
// window-order row -> token row
DEV int tok_of(int r){
  int win = r>>9, nn = r&511;
  int bh = win>>4, bw=(win>>2)&3, bd=win&3;
  int ih = nn>>6,  iw=(nn>>3)&7,  id=nn&7;
  return ((bh*8+ih)<<10) | ((bw*8+iw)<<5) | (bd*8+id);
}

// ---------------- small prep kernels ----------------

// dst bf16 [N][K] = transpose(src fp32 [K][N])
__global__ void wtr_k(const float* __restrict__ w, u16* __restrict__ wt, int K, int N){
  int f = blockIdx.x*256 + threadIdx.x;
  if (f >= K*N) return;
  int n = f / K, k = f - n*K;
  wt[f] = f2b(w[(size_t)k*N + n]);
}

__global__ void conv_k(const float* __restrict__ x, u16* __restrict__ o, int n4){
  int stride = gridDim.x*blockDim.x;
  for (int i = blockIdx.x*blockDim.x + threadIdx.x; i < n4; i += stride){
    const float4 v = *(const float4*)(x + (size_t)i*4);
    u32 lo = (u32)f2b(v.x) | ((u32)f2b(v.y)<<16);
    u32 hi = (u32)f2b(v.z) | ((u32)f2b(v.w)<<16);
    *(uint2*)(o + (size_t)i*4) = make_uint2(lo, hi);
  }
}

// LayerNorm over 256 cols, one wave per row, writes bf16
__global__ __launch_bounds__(256)
void ln_k(const float* __restrict__ x, const float* __restrict__ g,
          const float* __restrict__ b, u16* __restrict__ out){
  int row  = blockIdx.x*4 + (threadIdx.x>>6);
  int lane = threadIdx.x & 63;
  const float4 v = *(const float4*)(x + (size_t)row*256 + lane*4);
  float s = v.x+v.y+v.z+v.w;
  #pragma unroll
  for (int m=1;m<64;m<<=1) s += __shfl_xor(s, m);
  float mean = s * (1.0f/256.0f);
  float d0=v.x-mean,d1=v.y-mean,d2=v.z-mean,d3=v.w-mean;
  float q = d0*d0+d1*d1+d2*d2+d3*d3;
  #pragma unroll
  for (int m=1;m<64;m<<=1) q += __shfl_xor(q, m);
  float rs = rsqrtf(q*(1.0f/256.0f) + 1e-5f);
  const float4 gg = *(const float4*)(g + lane*4);
  const float4 bb = *(const float4*)(b + lane*4);
  u32 lo = (u32)f2b(d0*rs*gg.x+bb.x) | ((u32)f2b(d1*rs*gg.y+bb.y)<<16);
  u32 hi = (u32)f2b(d2*rs*gg.z+bb.z) | ((u32)f2b(d3*rs*gg.w+bb.w)<<16);
  *(uint2*)(out + (size_t)row*256 + lane*4) = make_uint2(lo,hi);
}

// position-bias MLP: one thread per table row (3375 rows)
template<int NOUT>
DEV void pstage(float* v, const float* g, const float* b, const float* W, const float* bb){
  float m = 0.f;
  #pragma unroll
  for (int i=0;i<16;i++) m += v[i];
  m *= 0.0625f;
  float q = 0.f;
  #pragma unroll
  for (int i=0;i<16;i++){ float d=v[i]-m; q += d*d; }
  float rs = rsqrtf(q*0.0625f + 1e-5f);
  float u[16];
  #pragma unroll
  for (int i=0;i<16;i++){ float t = (v[i]-m)*rs*g[i] + b[i]; u[i] = t>0.f?t:0.f; }
  #pragma unroll
  for (int o=0;o<NOUT;o++){
    float s = bb[o];
    #pragma unroll
    for (int kk=0;kk<16;kk++) s += u[kk]*W[kk*NOUT+o];
    v[o] = s;
  }
}

__global__ void posmlp_k(const float* pp_w, const float* pp_b,
                         const float* g1, const float* b1, const float* w1, const float* bb1,
                         const float* g2, const float* b2, const float* w2, const float* bb2,
                         const float* g3, const float* b3, const float* w3, const float* bb3,
                         float* __restrict__ pos){
  int i = blockIdx.x*256 + threadIdx.x;
  if (i >= 3375) return;
  int t = i;
  int bd = t % 15; t /= 15;
  int bw = t % 15; t /= 15;
  int bh = t;
  float fh = (float)(bh-7), fw = (float)(bw-7), fd = (float)(bd-7);
  float v[16];
  #pragma unroll
  for (int o=0;o<16;o++) v[o] = fh*pp_w[o] + fw*pp_w[16+o] + fd*pp_w[32+o] + pp_b[o];
  pstage<16>(v, g1,b1,w1,bb1);
  pstage<16>(v, g2,b2,w2,bb2);
  pstage<8> (v, g3,b3,w3,bb3);
  #pragma unroll
  for (int h=0;h<8;h++) pos[(size_t)i*8 + h] = v[h];
}

// expand bias into S^T MFMA-fragment layout:
// biasF[h][qc(32)][nc(32)][lane(64)][j(4)] = bias[q=qc*16+(lane&15)][n=nc*16+(lane>>4)*4+j]
__global__ void biasx_k(const float* __restrict__ pos, u16* __restrict__ biasF){
  int f = blockIdx.x*256 + threadIdx.x;    // 2,097,152 total
  int j = f&3, ln = (f>>2)&63, nc = (f>>8)&31, qc = (f>>13)&31, h = f>>18;
  int q = qc*16 + (ln&15);
  int k = nc*16 + ((ln>>4)<<2) + j;
  int rh = (q>>6) - (k>>6) + 7;
  int rw = ((q>>3)&7) - ((k>>3)&7) + 7;
  int rd = (q&7) - (k&7) + 7;
  int idx = (rh*15 + rw)*15 + rd;
  biasF[f] = f2b(pos[idx*8 + h]);
}

// ---------------- GEMM: C[M][·] = A[M][K](bf16) @ Bt[N][K](bf16)^T, per-mode epilogue ----------------
struct GemmP {
  const u16* A; const u16* Bt;
  int K;
  const float* bvec;
  float scale;
  const float* add32;
  float* out32;
  u16* out16;
  u16* out16b;
};

template<int MODE>
__global__ __launch_bounds__(256)
void gemm_k(GemmP p){
  __shared__ u16 lA[2][4096];
  __shared__ u16 lB[2][4096];
  const int tid = threadIdx.x;
  const int wid = tid>>6, lane = tid&63;
  const int lr = lane&15, lg = lane>>4;
  const int m0 = blockIdx.x*128, n0 = blockIdx.y*128;
  const int K = p.K;
  const int nt = K>>5;
  const int wm = (wid>>1)*64, wn = (wid&1)*64;
  const f32x4 z4 = {0.f,0.f,0.f,0.f};

  f32x4 acc[4][4];
  #pragma unroll
  for (int i=0;i<4;i++)
    #pragma unroll
    for (int j=0;j<4;j++) acc[i][j] = z4;

  // prologue stage (t = 0)
  #pragma unroll
  for (int r=0;r<2;r++){
    int off = (r*256 + tid)*16;
    int row = off>>6, kc = (off&63)>>1;
    gll16(p.A  + (size_t)(m0+row)*K + kc, (char*)lA[0] + off);
    gll16(p.Bt + (size_t)(n0+row)*K + kc, (char*)lB[0] + off);
  }
  __syncthreads();
  int cur = 0;
  for (int t=0; t<nt; ++t){
    if (t+1 < nt){
      int k0 = (t+1)<<5;
      #pragma unroll
      for (int r=0;r<2;r++){
        int off = (r*256 + tid)*16;
        int row = off>>6, kc = (off&63)>>1;
        gll16(p.A  + (size_t)(m0+row)*K + k0 + kc, (char*)lA[cur^1] + off);
        gll16(p.Bt + (size_t)(n0+row)*K + k0 + kc, (char*)lB[cur^1] + off);
      }
    }
    bf16x8 af[4], bfr[4];
    #pragma unroll
    for (int i=0;i<4;i++){
      af[i]  = *(const bf16x8*)&lA[cur][(wm + i*16 + lr)*32 + lg*8];
      bfr[i] = *(const bf16x8*)&lB[cur][(wn + i*16 + lr)*32 + lg*8];
    }
    #pragma unroll
    for (int i=0;i<4;i++)
      #pragma unroll
      for (int j=0;j<4;j++)
        acc[i][j] = __builtin_amdgcn_mfma_f32_16x16x32_bf16(af[i], bfr[j], acc[i][j], 0,0,0);
    __syncthreads();
    cur ^= 1;
  }

  // epilogue: D layout col=lane&15, row=(lane>>4)*4+v  [verified m89]
  #pragma unroll
  for (int i=0;i<4;i++){
    #pragma unroll
    for (int j=0;j<4;j++){
      #pragma unroll
      for (int v=0;v<4;v++){
        int r = m0 + wm + i*16 + lg*4 + v;
        int c = n0 + wn + j*16 + lr;
        float val = acc[i][j][v];
        if constexpr (MODE==0){           // Q: (val+b)*scale -> Q[win*8+h][n][d]
          float qv = (val + p.bvec[c]) * p.scale;
          int win, n; win_n(r, win, n);
          int hh = c>>5, dd = c&31;
          p.out16[((size_t)((win*8+hh)*512 + n)<<5) + dd] = f2b(qv);
        } else if constexpr (MODE==1){    // K (c<256) / V (c>=256), MFMA fragment layout
          float ov = val + p.bvec[c];
          int win, n; win_n(r, win, n);
          int cc = c & 255;
          int hh = cc>>5, dd = cc&31;
          size_t base = (size_t)(win*8+hh)*16384;
          if (c < 256){
            // K frag: [nc][lane][8] : K[n=nc*16+(ln&15)][d=(ln>>4)*8+j]
            int nc = n>>4, ln2 = ((dd>>3)<<4)|(n&15), jj = dd&7;
            p.out16[base + (size_t)(nc*64+ln2)*8 + jj] = f2b(ov);
          } else {
            // V frag: [kc*2+dblk][lane][8] : V[n=kc*32+(ln>>4)*8+j][d=dblk*16+(ln&15)]
            int fi = ((n>>5)<<1) | (dd>>4);
            int ln2 = (((n>>3)&3)<<4)|(dd&15), jj = n&7;
            p.out16b[base + (size_t)(fi*64+ln2)*8 + jj] = f2b(ov);
          }
        } else if constexpr (MODE==2){    // proj + x residual, window row -> token row
          int l = tok_of(r);
          size_t o = (size_t)l*256 + c;
          p.out32[o] = val + p.bvec[c] + p.add32[o];
        } else if constexpr (MODE==3){    // fc1 + exact GELU
          float u = val + p.bvec[c];
          float ge = 0.5f*u*(1.0f + erff(u*0.70710678118654752f));
          p.out16[(size_t)r*1024 + c] = f2b(ge);
        } else {                          // fc2 + residual -> fp32 out
          size_t o = (size_t)r*256 + c;
          p.out32[o] = val + p.bvec[c] + p.add32[o];
        }
      }
    }
  }
}

// ---------------- attention: one block per (window, head), 8 waves, flash 2-phase ----------------
// S^T = mfma(Kfrag, Qfrag): lane owns one q-row; softmax lane-local with online rescale;
// P -> A-frag via cvt_pk + permlane32/16 swaps; all LDS reads wave-contiguous.
__global__ __launch_bounds__(512, 4)
void attn_k(const u16* __restrict__ Q, const u16* __restrict__ Kf,
            const u16* __restrict__ Vf, const u16* __restrict__ biasF,
            u16* __restrict__ out){
  __shared__ u16 lK[16384];      // 32 frags x 1KB, fragment order
  __shared__ u16 lV[16384];      // 32 frags x 1KB (16 kc x 2 dblk)
  const int bid = blockIdx.x;
  const int win = bid>>3, hh = bid&7;
  const int tid = threadIdx.x, wid = tid>>6, lane = tid&63;
  const int lr = lane&15, lg = lane>>4;
  const u16* Kb = Kf + (size_t)bid*16384;
  const u16* Vb = Vf + (size_t)bid*16384;
  const u16* Qb = Q  + (size_t)bid*16384;
  #pragma unroll
  for (int r=0;r<4;r++){
    int off = (r*512 + tid)*16;
    gll16((const char*)Kb + off, (char*)lK + off);
    gll16((const char*)Vb + off, (char*)lV + off);
  }
  __syncthreads();
  const u16* bF = biasF + ((size_t)hh<<18);
  const f32x4 z4 = {0.f,0.f,0.f,0.f};

  for (int ch=0; ch<4; ++ch){
    const int r0 = wid*64 + ch*16;
    const int qc = r0>>4;
    bf16x8 qf = *(const bf16x8*)(Qb + (size_t)(r0+lr)*32 + lg*8);
    const u16* bq = bF + ((size_t)qc<<13) + lane*4;
    f32x4 o0 = z4, o1 = z4;
    float m = -3.0e38f, s = 0.f;
    #pragma unroll
    for (int ph=0; ph<2; ++ph){
      // S^T frags for this half: sf[i][v] = S[q=r0+lr][n=(ph*16+i)*16+lg*4+v]
      f32x4 sf[16];
      #pragma unroll
      for (int i=0;i<16;i++){
        int nc = ph*16 + i;
        bf16x8 kf = *(const bf16x8*)&lK[(nc*64 + lane)*8];
        sf[i] = __builtin_amdgcn_mfma_f32_16x16x32_bf16(kf, qf, z4, 0,0,0);
      }
      #pragma unroll
      for (int i=0;i<16;i++){
        uint2 bv = *(const uint2*)(bq + (ph*16+i)*256);
        sf[i][0] += b2f((u16)(bv.x & 0xffffu));
        sf[i][1] += b2f((u16)(bv.x >> 16));
        sf[i][2] += b2f((u16)(bv.y & 0xffffu));
        sf[i][3] += b2f((u16)(bv.y >> 16));
      }
      // row max of this half (row q=r0+lr per lane; combine lg groups)
      float pm = -3.0e38f;
      #pragma unroll
      for (int i=0;i<16;i++)
        pm = fmaxf(pm, fmaxf(fmaxf(sf[i][0],sf[i][1]), fmaxf(sf[i][2],sf[i][3])));
      pm = fmaxf(pm, __shfl_xor(pm,16));
      pm = fmaxf(pm, __shfl_xor(pm,32));
      float mn = fmaxf(m, pm);
      if (ph){
        float f = __expf(m - mn);      // per-row (row = r0+lr) factor
        s *= f;
        float f0 = __shfl(f, lg*4+0), f1 = __shfl(f, lg*4+1);
        float f2 = __shfl(f, lg*4+2), f3 = __shfl(f, lg*4+3);
        o0[0]*=f0; o0[1]*=f1; o0[2]*=f2; o0[3]*=f3;
        o1[0]*=f0; o1[1]*=f1; o1[2]*=f2; o1[3]*=f3;
      }
      m = mn;
      float ls = 0.f;
      #pragma unroll
      for (int i=0;i<16;i++){
        #pragma unroll
        for (int v=0;v<4;v++){ float e = __expf(sf[i][v]-m); sf[i][v]=e; ls+=e; }
      }
      ls += __shfl_xor(ls,16);
      ls += __shfl_xor(ls,32);
      s += ls;
      // PV over this half's 8 kc blocks
      #pragma unroll
      for (int kc=0;kc<8;kc++){
        u32 a0 = pk2(sf[2*kc  ][0], sf[2*kc  ][1]);
        u32 a1 = pk2(sf[2*kc  ][2], sf[2*kc  ][3]);
        u32 b0 = pk2(sf[2*kc+1][0], sf[2*kc+1][1]);
        u32 b1 = pk2(sf[2*kc+1][2], sf[2*kc+1][3]);
        asm("v_permlane32_swap_b32 %0, %1" : "+v"(a0), "+v"(b0));
        asm("v_permlane16_swap_b32 %0, %1" : "+v"(a0), "+v"(b0));  // a0=T0, b0=T2
        asm("v_permlane32_swap_b32 %0, %1" : "+v"(a1), "+v"(b1));
        asm("v_permlane16_swap_b32 %0, %1" : "+v"(a1), "+v"(b1));  // a1=T1, b1=T3
        bf16x8 pf;
        ((u32*)&pf)[0]=a0; ((u32*)&pf)[1]=a1; ((u32*)&pf)[2]=b0; ((u32*)&pf)[3]=b1;
        int kcg = ph*8 + kc;
        bf16x8 v0 = *(const bf16x8*)&lV[(size_t)((kcg*2+0)*64 + lane)*8];
        bf16x8 v1 = *(const bf16x8*)&lV[(size_t)((kcg*2+1)*64 + lane)*8];
        o0 = __builtin_amdgcn_mfma_f32_16x16x32_bf16(pf, v0, o0, 0,0,0);
        o1 = __builtin_amdgcn_mfma_f32_16x16x32_bf16(pf, v1, o1, 0,0,0);
      }
    }
    #pragma unroll
    for (int v=0;v<4;v++){
      float inv = 1.0f / __shfl(s, lg*4+v);
      int n = r0 + lg*4 + v;
      size_t base = ((size_t)(win*512 + n))*256 + hh*32;
      out[base + lr]      = f2b(o0[v]*inv);
      out[base + 16 + lr] = f2b(o1[v]*inv);
    }
  }
}

// ---------------- host launch ----------------
extern "C" void kernel_launch(void* const* d_in, const int* in_sizes, int n_in,
                              void* d_out, int out_size, void* d_ws, size_t ws_size,
                              hipStream_t stream){
  const float* x      = (const float*)d_in[0];
  const float* y      = (const float*)d_in[1];
  const float* n1_g   = (const float*)d_in[2];
  const float* n1_b   = (const float*)d_in[3];
  const float* qkv_w  = (const float*)d_in[4];
  const float* qkv_b  = (const float*)d_in[5];
  const float* pp_w   = (const float*)d_in[6];
  const float* pp_b   = (const float*)d_in[7];
  const float* p1_lng = (const float*)d_in[8];
  const float* p1_lnb = (const float*)d_in[9];
  const float* p1_w   = (const float*)d_in[10];
  const float* p1_b   = (const float*)d_in[11];
  const float* p2_lng = (const float*)d_in[12];
  const float* p2_lnb = (const float*)d_in[13];
  const float* p2_w   = (const float*)d_in[14];
  const float* p2_b   = (const float*)d_in[15];
  const float* p3_lng = (const float*)d_in[16];
  const float* p3_lnb = (const float*)d_in[17];
  const float* p3_w   = (const float*)d_in[18];
  const float* p3_b   = (const float*)d_in[19];
  const float* proj_w = (const float*)d_in[20];
  const float* proj_b = (const float*)d_in[21];
  const float* n2_g   = (const float*)d_in[22];
  const float* n2_b   = (const float*)d_in[23];
  const float* fc1_w  = (const float*)d_in[24];
  const float* fc1_b  = (const float*)d_in[25];
  const float* fc2_w  = (const float*)d_in[26];
  const float* fc2_b  = (const float*)d_in[27];
  float* out = (float*)d_out;
  char* ws = (char*)d_ws;

  // workspace layout (bytes)
  u16*   qkvT  = (u16*)  (ws + 0);          // [768][256] bf16
  u16*   projT = (u16*)  (ws + 393216);     // [256][256]
  u16*   fc1T  = (u16*)  (ws + 524288);     // [1024][256]
  u16*   fc2T  = (u16*)  (ws + 1048576);    // [256][1024]
  float* pos   = (float*)(ws + 1572864);    // [3375][8] fp32
  u16*   biasF = (u16*)  (ws + 1703936);    // 2,097,152 bf16
  u16*   xn    = (u16*)  (ws + 5898240);    // [32768][256]
  u16*   yb    = (u16*)  (ws + 22675456);
  u16*   Qb    = (u16*)  (ws + 39452672);   // [512 bh][512 n][32 d]
  u16*   Kfb   = (u16*)  (ws + 56229888);   // [512 bh][32 frag][64 lane][8]
  u16*   Vfb   = (u16*)  (ws + 73007104);   // [512 bh][32 frag][64 lane][8]
  u16*   attn  = (u16*)  (ws + 89784320);   // [32768][256] window-row order
  float* xres  = (float*)(ws + 106561536);  // [32768][256] fp32   (end 140,115,968)
  u16*   hbuf  = xn;     // alias: MLP hidden [32768][1024], xn/yb/Qb dead by then
  u16*   x2n   = attn;   // alias: LN2 output, attn dead after proj

  wtr_k<<<768, 256,0,stream>>>(qkv_w, qkvT, 256, 768);
  wtr_k<<<256, 256,0,stream>>>(proj_w, projT, 256, 256);
  wtr_k<<<1024,256,0,stream>>>(fc1_w, fc1T, 256, 1024);
  wtr_k<<<1024,256,0,stream>>>(fc2_w, fc2T, 1024, 256);
  posmlp_k<<<14,256,0,stream>>>(pp_w, pp_b,
                                p1_lng,p1_lnb,p1_w,p1_b,
                                p2_lng,p2_lnb,p2_w,p2_b,
                                p3_lng,p3_lnb,p3_w,p3_b, pos);
  biasx_k<<<8192,256,0,stream>>>(pos, biasF);
  ln_k<<<8192,256,0,stream>>>(x, n1_g, n1_b, xn);
  conv_k<<<2048,256,0,stream>>>(y, yb, 2097152);

  GemmP pq; pq.A=xn; pq.Bt=qkvT; pq.K=256; pq.bvec=qkv_b;
  pq.scale=0.17677669529663687f; pq.add32=nullptr; pq.out32=nullptr; pq.out16=Qb; pq.out16b=nullptr;
  gemm_k<0><<<dim3(256,2),256,0,stream>>>(pq);

  GemmP pkv; pkv.A=yb; pkv.Bt=qkvT + 256*256; pkv.K=256; pkv.bvec=qkv_b + 256;
  pkv.scale=1.f; pkv.add32=nullptr; pkv.out32=nullptr; pkv.out16=Kfb; pkv.out16b=Vfb;
  gemm_k<1><<<dim3(256,4),256,0,stream>>>(pkv);

  attn_k<<<512,512,0,stream>>>(Qb, Kfb, Vfb, biasF, attn);

  GemmP pp; pp.A=attn; pp.Bt=projT; pp.K=256; pp.bvec=proj_b;
  pp.scale=1.f; pp.add32=x; pp.out32=xres; pp.out16=nullptr; pp.out16b=nullptr;
  gemm_k<2><<<dim3(256,2),256,0,stream>>>(pp);

  ln_k<<<8192,256,0,stream>>>(xres, n2_g, n2_b, x2n);

  GemmP pf1; pf1.A=x2n; pf1.Bt=fc1T; pf1.K=256; pf1.bvec=fc1_b;
  pf1.scale=1.f; pf1.add32=nullptr; pf1.out32=nullptr; pf1.out16=hbuf; pf1.out16b=nullptr;
  gemm_k<3><<<dim3(256,8),256,0,stream>>>(pf1);

  GemmP pf2; pf2.A=hbuf; pf2.Bt=fc2T; pf2.K=1024; pf2.bvec=fc2_b;
  pf2.scale=1.f; pf2.add32=xres; pf2.out32=out; pf2.out16=nullptr; pf2.out16b=nullptr;
  gemm_k<4><<<dim3(256,2),256,0,stream>>>(pf2);
}

// Round 4
// 310.323 us; speedup vs baseline: 1.3237x; 1.1113x over previous
//
#include <hip/hip_runtime.h>
#include <cstdint>
#include <cstddef>

typedef unsigned int u32;
typedef unsigned short u16;
typedef __attribute__((ext_vector_type(8))) short bf16x8;   // 8 bf16 = 4 VGPR
typedef __attribute__((ext_vector_type(4))) float f32x4;

#define DEV __device__ __forceinline__

DEV float b2f(u16 u){ return __uint_as_float(((u32)u)<<16); }
DEV u16 f2b(float f){ u32 x = __float_as_uint(f); x += 0x7fffu + ((x>>16)&1u); return (u16)(x>>16); }
DEV u32 pk2(float a, float b){
  u32 r;
  asm("v_cvt_pk_bf16_f32 %0, %1, %2" : "=v"(r) : "v"(a), "v"(b));
  return r;
}

DEV void gll16(const void* g, void* l){
  __builtin_amdgcn_global_load_lds((const __attribute__((address_space(1))) u32*)g,
                                   (__attribute__((address_space(3))) u32*)l, 16, 0, 0);
}

// token row -> (window, in-window index);  H=W=D=32, g=8
DEV void win_n(int r, int& win, int& n){
  int d_ = r & 31, w_ = (r>>5)&31, h_ = r>>10;
  win = ((h_>>3)<<4) | ((w_>>3)<<2) | (d_>>3);
  n   = ((h_&7)<<6)  | ((w_&7)<<3)  | (d_&7);
}
// window-order row -> token row
DEV int tok_of(int r){
  int win = r>>9, nn = r&511;
  int bh = win>>4, bw=(win>>2)&3, bd=win&3;
  int ih = nn>>6,  iw=(nn>>3)&7,  id=nn&7;
  return ((bh*8+ih)<<10) | ((bw*8+iw)<<5) | (bd*8+id);
}

// ---------------- small prep kernels ----------------

// dst bf16 [N][K] = transpose(src fp32 [K][N])
__global__ void wtr_k(const float* __restrict__ w, u16* __restrict__ wt, int K, int N){
  int f = blockIdx.x*256 + threadIdx.x;
  if (f >= K*N) return;
  int n = f / K, k = f - n*K;
  wt[f] = f2b(w[(size_t)k*N + n]);
}

__global__ void conv_k(const float* __restrict__ x, u16* __restrict__ o, int n4){
  int stride = gridDim.x*blockDim.x;
  for (int i = blockIdx.x*blockDim.x + threadIdx.x; i < n4; i += stride){
    const float4 v = *(const float4*)(x + (size_t)i*4);
    u32 lo = (u32)f2b(v.x) | ((u32)f2b(v.y)<<16);
    u32 hi = (u32)f2b(v.z) | ((u32)f2b(v.w)<<16);
    *(uint2*)(o + (size_t)i*4) = make_uint2(lo, hi);
  }
}

// LayerNorm over 256 cols, one wave per row, writes bf16
__global__ __launch_bounds__(256)
void ln_k(const float* __restrict__ x, const float* __restrict__ g,
          const float* __restrict__ b, u16* __restrict__ out){
  int row  = blockIdx.x*4 + (threadIdx.x>>6);
  int lane = threadIdx.x & 63;
  const float4 v = *(const float4*)(x + (size_t)row*256 + lane*4);
  float s = v.x+v.y+v.z+v.w;
  #pragma unroll
  for (int m=1;m<64;m<<=1) s += __shfl_xor(s, m);
  float mean = s * (1.0f/256.0f);
  float d0=v.x-mean,d1=v.y-mean,d2=v.z-mean,d3=v.w-mean;
  float q = d0*d0+d1*d1+d2*d2+d3*d3;
  #pragma unroll
  for (int m=1;m<64;m<<=1) q += __shfl_xor(q, m);
  float rs = rsqrtf(q*(1.0f/256.0f) + 1e-5f);
  const float4 gg = *(const float4*)(g + lane*4);
  const float4 bb = *(const float4*)(b + lane*4);
  u32 lo = (u32)f2b(d0*rs*gg.x+bb.x) | ((u32)f2b(d1*rs*gg.y+bb.y)<<16);
  u32 hi = (u32)f2b(d2*rs*gg.z+bb.z) | ((u32)f2b(d3*rs*gg.w+bb.w)<<16);
  *(uint2*)(out + (size_t)row*256 + lane*4) = make_uint2(lo,hi);
}

// position-bias MLP: one thread per table row (3375 rows); emits bf16 per-head tables
template<int NOUT>
DEV void pstage(float* v, const float* g, const float* b, const float* W, const float* bb){
  float m = 0.f;
  #pragma unroll
  for (int i=0;i<16;i++) m += v[i];
  m *= 0.0625f;
  float q = 0.f;
  #pragma unroll
  for (int i=0;i<16;i++){ float d=v[i]-m; q += d*d; }
  float rs = rsqrtf(q*0.0625f + 1e-5f);
  float u[16];
  #pragma unroll
  for (int i=0;i<16;i++){ float t = (v[i]-m)*rs*g[i] + b[i]; u[i] = t>0.f?t:0.f; }
  #pragma unroll
  for (int o=0;o<NOUT;o++){
    float s = bb[o];
    #pragma unroll
    for (int kk=0;kk<16;kk++) s += u[kk]*W[kk*NOUT+o];
    v[o] = s;
  }
}

__global__ void posmlp_k(const float* pp_w, const float* pp_b,
                         const float* g1, const float* b1, const float* w1, const float* bb1,
                         const float* g2, const float* b2, const float* w2, const float* bb2,
                         const float* g3, const float* b3, const float* w3, const float* bb3,
                         u16* __restrict__ posb){
  int i = blockIdx.x*256 + threadIdx.x;
  if (i >= 3375) return;
  int t = i;
  int bd = t % 15; t /= 15;
  int bw = t % 15; t /= 15;
  int bh = t;
  float fh = (float)(bh-7), fw = (float)(bw-7), fd = (float)(bd-7);
  float v[16];
  #pragma unroll
  for (int o=0;o<16;o++) v[o] = fh*pp_w[o] + fw*pp_w[16+o] + fd*pp_w[32+o] + pp_b[o];
  pstage<16>(v, g1,b1,w1,bb1);
  pstage<16>(v, g2,b2,w2,bb2);
  pstage<8> (v, g3,b3,w3,bb3);
  #pragma unroll
  for (int h=0;h<8;h++) posb[(size_t)h*3376 + i] = f2b(v[h]);
}

// ---------------- GEMM: C[M][·] = A[M][K](bf16) @ Bt[N][K](bf16)^T, per-mode epilogue ----------------
struct GemmP {
  const u16* A; const u16* Bt;
  int K;
  const float* bvec;
  float scale;
  const float* add32;
  float* out32;
  u16* out16;
  u16* out16b;
};

template<int MODE>
__global__ __launch_bounds__(256)
void gemm_k(GemmP p){
  __shared__ u16 lA[2][4096];
  __shared__ u16 lB[2][4096];
  const int tid = threadIdx.x;
  const int wid = tid>>6, lane = tid&63;
  const int lr = lane&15, lg = lane>>4;
  const int m0 = blockIdx.x*128, n0 = blockIdx.y*128;
  const int K = p.K;
  const int nt = K>>5;
  const int wm = (wid>>1)*64, wn = (wid&1)*64;
  const f32x4 z4 = {0.f,0.f,0.f,0.f};

  // MODE 2: A is attnF [win*8+h][512 n][32 d]; row r=(m0+row) is window-order token,
  // col = k0+kc -> head k0>>5, within-head d = kc.
  auto srcA = [&](int row, int kcol)->const u16*{
    if constexpr (MODE==2){
      int rr = m0 + row;
      return p.A + ((size_t)((rr>>9)*8 + (kcol>>5))*512 + (rr&511))*32 + (kcol&31);
    } else {
      return p.A + (size_t)(m0+row)*K + kcol;
    }
  };

  f32x4 acc[4][4];
  #pragma unroll
  for (int i=0;i<4;i++)
    #pragma unroll
    for (int j=0;j<4;j++) acc[i][j] = z4;

  // prologue stage (t = 0)
  #pragma unroll
  for (int r=0;r<2;r++){
    int off = (r*256 + tid)*16;
    int row = off>>6, kc = (off&63)>>1;
    gll16(srcA(row, kc), (char*)lA[0] + off);
    gll16(p.Bt + (size_t)(n0+row)*K + kc, (char*)lB[0] + off);
  }
  __syncthreads();
  int cur = 0;
  for (int t=0; t<nt; ++t){
    if (t+1 < nt){
      int k0 = (t+1)<<5;
      #pragma unroll
      for (int r=0;r<2;r++){
        int off = (r*256 + tid)*16;
        int row = off>>6, kc = (off&63)>>1;
        gll16(srcA(row, k0+kc), (char*)lA[cur^1] + off);
        gll16(p.Bt + (size_t)(n0+row)*K + k0 + kc, (char*)lB[cur^1] + off);
      }
    }
    bf16x8 af[4], bfr[4];
    #pragma unroll
    for (int i=0;i<4;i++){
      af[i]  = *(const bf16x8*)&lA[cur][(wm + i*16 + lr)*32 + lg*8];
      bfr[i] = *(const bf16x8*)&lB[cur][(wn + i*16 + lr)*32 + lg*8];
    }
    #pragma unroll
    for (int i=0;i<4;i++)
      #pragma unroll
      for (int j=0;j<4;j++)
        acc[i][j] = __builtin_amdgcn_mfma_f32_16x16x32_bf16(af[i], bfr[j], acc[i][j], 0,0,0);
    __syncthreads();
    cur ^= 1;
  }

  // epilogue: D layout col=lane&15, row=(lane>>4)*4+v  [verified m89]
  #pragma unroll
  for (int i=0;i<4;i++){
    #pragma unroll
    for (int j=0;j<4;j++){
      #pragma unroll
      for (int v=0;v<4;v++){
        int r = m0 + wm + i*16 + lg*4 + v;
        int c = n0 + wn + j*16 + lr;
        float val = acc[i][j][v];
        if constexpr (MODE==0){           // Q: (val+b)*scale -> Q[win*8+h][n][d]
          float qv = (val + p.bvec[c]) * p.scale;
          int win, n; win_n(r, win, n);
          int hh = c>>5, dd = c&31;
          p.out16[((size_t)((win*8+hh)*512 + n)<<5) + dd] = f2b(qv);
        } else if constexpr (MODE==1){    // K (c<256) / V (c>=256), MFMA fragment layout
          float ov = val + p.bvec[c];
          int win, n; win_n(r, win, n);
          int cc = c & 255;
          int hh = cc>>5, dd = cc&31;
          size_t base = (size_t)(win*8+hh)*16384;
          if (c < 256){
            // K frag: [nc][lane][8] : K[n=nc*16+(ln&15)][d=(ln>>4)*8+j]
            int nc = n>>4, ln2 = ((dd>>3)<<4)|(n&15), jj = dd&7;
            p.out16[base + (size_t)(nc*64+ln2)*8 + jj] = f2b(ov);
          } else {
            // V frag: [kc*2+dblk][lane][8] : V[n=kc*32+(ln>>4)*8+j][d=dblk*16+(ln&15)]
            int fi = ((n>>5)<<1) | (dd>>4);
            int ln2 = (((n>>3)&3)<<4)|(dd&15), jj = n&7;
            p.out16b[base + (size_t)(fi*64+ln2)*8 + jj] = f2b(ov);
          }
        } else if constexpr (MODE==2){    // proj + x residual, window row -> token row
          int l = tok_of(r);
          size_t o = (size_t)l*256 + c;
          p.out32[o] = val + p.bvec[c] + p.add32[o];
        } else if constexpr (MODE==3){    // fc1 + exact GELU
          float u = val + p.bvec[c];
          float ge = 0.5f*u*(1.0f + erff(u*0.70710678118654752f));
          p.out16[(size_t)r*1024 + c] = f2b(ge);
        } else {                          // fc2 + residual -> fp32 out
          size_t o = (size_t)r*256 + c;
          p.out32[o] = val + p.bvec[c] + p.add32[o];
        }
      }
    }
  }
}

// ---------------- attention: one block per (window, head), 8 waves, flash 2-phase ----------------
// S^T = mfma(Kfrag, Qfrag): lane owns one q-row; bias computed in-kernel from the
// 3375-entry per-head pos table (LDS, dual parity copies -> two aligned b32 per frag);
// P -> A-frag via cvt_pk + permlane32/16 swaps; output block-contiguous [bh][n][32].
__global__ __launch_bounds__(512, 4)
void attn_k(const u16* __restrict__ Q, const u16* __restrict__ Kf,
            const u16* __restrict__ Vf, const u16* __restrict__ posb,
            u16* __restrict__ outF){
  __shared__ u16 lK[16384];      // 32 frags x 1KB, fragment order
  __shared__ u16 lV[16384];      // 32 frags x 1KB (16 kc x 2 dblk)
  __shared__ u16 lP[2][3392];    // pos table, copy1 shifted by +1 element (parity align)
  const int bid = blockIdx.x;
  const int hh = bid&7;
  const int tid = threadIdx.x, wid = tid>>6, lane = tid&63;
  const int lr = lane&15, lg = lane>>4;
  const u16* Kb = Kf + (size_t)bid*16384;
  const u16* Vb = Vf + (size_t)bid*16384;
  const u16* Qb = Q  + (size_t)bid*16384;
  #pragma unroll
  for (int r=0;r<4;r++){
    int off = (r*512 + tid)*16;
    gll16((const char*)Kb + off, (char*)lK + off);
    gll16((const char*)Vb + off, (char*)lV + off);
  }
  const u16* ptab = posb + (size_t)hh*3376;
  for (int t=tid; t<3375; t+=512){
    u16 u = ptab[t];
    lP[0][t]   = u;
    lP[1][t+1] = u;
  }
  __syncthreads();
  const f32x4 z4 = {0.f,0.f,0.f,0.f};

  for (int ch=0; ch<4; ++ch){
    const int r0 = wid*64 + ch*16;
    const int q  = r0 + lr;
    // bias index base: idx(nc,v) = Ab - (nc>>2)*225 - (nc&3)*30 - v
    const int Ab = (q>>6)*225 + ((q>>3)&7)*15 + (q&7) + 1687 - (lg>>1)*15 - (lg&1)*4;
    bf16x8 qf = *(const bf16x8*)(Qb + (size_t)q*32 + lg*8);
    f32x4 o0 = z4, o1 = z4;
    float m = -3.0e38f, s = 0.f;
    #pragma unroll
    for (int ph=0; ph<2; ++ph){
      // S^T frags for this half: sf[i][v] = S[q=r0+lr][n=(ph*16+i)*16+lg*4+v]
      f32x4 sf[16];
      #pragma unroll
      for (int i=0;i<16;i++){
        int nc = ph*16 + i;
        bf16x8 kf = *(const bf16x8*)&lK[(nc*64 + lane)*8];
        sf[i] = __builtin_amdgcn_mfma_f32_16x16x32_bf16(kf, qf, z4, 0,0,0);
      }
      // + bias via LDS gather: pos[idx0-3..idx0] = two aligned b32 from parity copy
      #pragma unroll
      for (int i=0;i<16;i++){
        int nc = ph*16 + i;
        int idx0 = Ab - (nc>>2)*225 - (nc&3)*30;
        int par = (idx0+1)&1;                       // parity of e1=idx0-3
        const char* bp = (const char*)lP + ((idx0-3)<<1) + par*6786;
        u32 u1 = *(const u32*)(bp);                 // (pos[idx0-3], pos[idx0-2])
        u32 u2 = *(const u32*)(bp + 4);             // (pos[idx0-1], pos[idx0])
        sf[i][3] += __uint_as_float(u1<<16);
        sf[i][2] += __uint_as_float(u1 & 0xffff0000u);
        sf[i][1] += __uint_as_float(u2<<16);
        sf[i][0] += __uint_as_float(u2 & 0xffff0000u);
      }
      // row max of this half (row q per lane; combine lg groups)
      float pm = -3.0e38f;
      #pragma unroll
      for (int i=0;i<16;i++)
        pm = fmaxf(pm, fmaxf(fmaxf(sf[i][0],sf[i][1]), fmaxf(sf[i][2],sf[i][3])));
      pm = fmaxf(pm, __shfl_xor(pm,16));
      pm = fmaxf(pm, __shfl_xor(pm,32));
      float mn = fmaxf(m, pm);
      if (ph){
        float f = __expf(m - mn);      // per-row factor
        s *= f;
        float f0 = __shfl(f, lg*4+0), f1 = __shfl(f, lg*4+1);
        float f2 = __shfl(f, lg*4+2), f3 = __shfl(f, lg*4+3);
        o0[0]*=f0; o0[1]*=f1; o0[2]*=f2; o0[3]*=f3;
        o1[0]*=f0; o1[1]*=f1; o1[2]*=f2; o1[3]*=f3;
      }
      m = mn;
      float ls = 0.f;
      #pragma unroll
      for (int i=0;i<16;i++){
        #pragma unroll
        for (int v=0;v<4;v++){ float e = __expf(sf[i][v]-m); sf[i][v]=e; ls+=e; }
      }
      ls += __shfl_xor(ls,16);
      ls += __shfl_xor(ls,32);
      s += ls;
      // PV over this half's 8 kc blocks
      #pragma unroll
      for (int kc=0;kc<8;kc++){
        u32 a0 = pk2(sf[2*kc  ][0], sf[2*kc  ][1]);
        u32 a1 = pk2(sf[2*kc  ][2], sf[2*kc  ][3]);
        u32 b0 = pk2(sf[2*kc+1][0], sf[2*kc+1][1]);
        u32 b1 = pk2(sf[2*kc+1][2], sf[2*kc+1][3]);
        asm("v_permlane32_swap_b32 %0, %1" : "+v"(a0), "+v"(b0));
        asm("v_permlane16_swap_b32 %0, %1" : "+v"(a0), "+v"(b0));  // a0=T0, b0=T2
        asm("v_permlane32_swap_b32 %0, %1" : "+v"(a1), "+v"(b1));
        asm("v_permlane16_swap_b32 %0, %1" : "+v"(a1), "+v"(b1));  // a1=T1, b1=T3
        bf16x8 pf;
        ((u32*)&pf)[0]=a0; ((u32*)&pf)[1]=a1; ((u32*)&pf)[2]=b0; ((u32*)&pf)[3]=b1;
        int kcg = ph*8 + kc;
        bf16x8 v0 = *(const bf16x8*)&lV[(size_t)((kcg*2+0)*64 + lane)*8];
        bf16x8 v1 = *(const bf16x8*)&lV[(size_t)((kcg*2+1)*64 + lane)*8];
        o0 = __builtin_amdgcn_mfma_f32_16x16x32_bf16(pf, v0, o0, 0,0,0);
        o1 = __builtin_amdgcn_mfma_f32_16x16x32_bf16(pf, v1, o1, 0,0,0);
      }
    }
    #pragma unroll
    for (int v=0;v<4;v++){
      float inv = 1.0f / __shfl(s, lg*4+v);
      int n = r0 + lg*4 + v;
      size_t base = ((size_t)bid*512 + n)*32;
      outF[base + lr]      = f2b(o0[v]*inv);
      outF[base + 16 + lr] = f2b(o1[v]*inv);
    }
  }
}

// ---------------- host launch ----------------
extern "C" void kernel_launch(void* const* d_in, const int* in_sizes, int n_in,
                              void* d_out, int out_size, void* d_ws, size_t ws_size,
                              hipStream_t stream){
  const float* x      = (const float*)d_in[0];
  const float* y      = (const float*)d_in[1];
  const float* n1_g   = (const float*)d_in[2];
  const float* n1_b   = (const float*)d_in[3];
  const float* qkv_w  = (const float*)d_in[4];
  const float* qkv_b  = (const float*)d_in[5];
  const float* pp_w   = (const float*)d_in[6];
  const float* pp_b   = (const float*)d_in[7];
  const float* p1_lng = (const float*)d_in[8];
  const float* p1_lnb = (const float*)d_in[9];
  const float* p1_w   = (const float*)d_in[10];
  const float* p1_b   = (const float*)d_in[11];
  const float* p2_lng = (const float*)d_in[12];
  const float* p2_lnb = (const float*)d_in[13];
  const float* p2_w   = (const float*)d_in[14];
  const float* p2_b   = (const float*)d_in[15];
  const float* p3_lng = (const float*)d_in[16];
  const float* p3_lnb = (const float*)d_in[17];
  const float* p3_w   = (const float*)d_in[18];
  const float* p3_b   = (const float*)d_in[19];
  const float* proj_w = (const float*)d_in[20];
  const float* proj_b = (const float*)d_in[21];
  const float* n2_g   = (const float*)d_in[22];
  const float* n2_b   = (const float*)d_in[23];
  const float* fc1_w  = (const float*)d_in[24];
  const float* fc1_b  = (const float*)d_in[25];
  const float* fc2_w  = (const float*)d_in[26];
  const float* fc2_b  = (const float*)d_in[27];
  float* out = (float*)d_out;
  char* ws = (char*)d_ws;

  // workspace layout (bytes)
  u16*   qkvT  = (u16*)  (ws + 0);          // [768][256] bf16
  u16*   projT = (u16*)  (ws + 393216);     // [256][256]
  u16*   fc1T  = (u16*)  (ws + 524288);     // [1024][256]
  u16*   fc2T  = (u16*)  (ws + 1048576);    // [256][1024]
  u16*   posb  = (u16*)  (ws + 1572864);    // [8][3376] bf16 per-head pos tables
  u16*   xn    = (u16*)  (ws + 5898240);    // [32768][256]
  u16*   yb    = (u16*)  (ws + 22675456);
  u16*   Qb    = (u16*)  (ws + 39452672);   // [512 bh][512 n][32 d]
  u16*   Kfb   = (u16*)  (ws + 56229888);   // [512 bh][32 frag][64 lane][8]
  u16*   Vfb   = (u16*)  (ws + 73007104);   // [512 bh][32 frag][64 lane][8]
  u16*   attnF = (u16*)  (ws + 89784320);   // [512 bh][512 n][32 d] block-contiguous
  float* xres  = (float*)(ws + 106561536);  // [32768][256] fp32   (end 140,115,968)
  u16*   hbuf  = xn;     // alias: MLP hidden [32768][1024], xn/yb/Qb dead by then
  u16*   x2n   = attnF;  // alias: LN2 output, attnF dead after proj

  wtr_k<<<768, 256,0,stream>>>(qkv_w, qkvT, 256, 768);
  wtr_k<<<256, 256,0,stream>>>(proj_w, projT, 256, 256);
  wtr_k<<<1024,256,0,stream>>>(fc1_w, fc1T, 256, 1024);
  wtr_k<<<1024,256,0,stream>>>(fc2_w, fc2T, 1024, 256);
  posmlp_k<<<14,256,0,stream>>>(pp_w, pp_b,
                                p1_lng,p1_lnb,p1_w,p1_b,
                                p2_lng,p2_lnb,p2_w,p2_b,
                                p3_lng,p3_lnb,p3_w,p3_b, posb);
  ln_k<<<8192,256,0,stream>>>(x, n1_g, n1_b, xn);
  conv_k<<<2048,256,0,stream>>>(y, yb, 2097152);

  GemmP pq; pq.A=xn; pq.Bt=qkvT; pq.K=256; pq.bvec=qkv_b;
  pq.scale=0.17677669529663687f; pq.add32=nullptr; pq.out32=nullptr; pq.out16=Qb; pq.out16b=nullptr;
  gemm_k<0><<<dim3(256,2),256,0,stream>>>(pq);

  GemmP pkv; pkv.A=yb; pkv.Bt=qkvT + 256*256; pkv.K=256; pkv.bvec=qkv_b + 256;
  pkv.scale=1.f; pkv.add32=nullptr; pkv.out32=nullptr; pkv.out16=Kfb; pkv.out16b=Vfb;
  gemm_k<1><<<dim3(256,4),256,0,stream>>>(pkv);

  attn_k<<<512,512,0,stream>>>(Qb, Kfb, Vfb, posb, attnF);

  GemmP pp; pp.A=attnF; pp.Bt=projT; pp.K=256; pp.bvec=proj_b;
  pp.scale=1.f; pp.add32=x; pp.out32=xres; pp.out16=nullptr; pp.out16b=nullptr;
  gemm_k<2><<<dim3(256,2),256,0,stream>>>(pp);

  ln_k<<<8192,256,0,stream>>>(xres, n2_g, n2_b, x2n);

  GemmP pf1; pf1.A=x2n; pf1.Bt=fc1T; pf1.K=256; pf1.bvec=fc1_b;
  pf1.scale=1.f; pf1.add32=nullptr; pf1.out32=nullptr; pf1.out16=hbuf; pf1.out16b=nullptr;
  gemm_k<3><<<dim3(256,8),256,0,stream>>>(pf1);

  GemmP pf2; pf2.A=hbuf; pf2.Bt=fc2T; pf2.K=1024; pf2.bvec=fc2_b;
  pf2.scale=1.f; pf2.add32=xres; pf2.out32=out; pf2.out16=nullptr; pf2.out16b=nullptr;
  gemm_k<4><<<dim3(256,2),256,0,stream>>>(pf2);
}

// Round 5
// 305.850 us; speedup vs baseline: 1.3431x; 1.0146x over previous
//
#include <hip/hip_runtime.h>
#include <cstdint>
#include <cstddef>

typedef unsigned int u32;
typedef unsigned short u16;
typedef __attribute__((ext_vector_type(8))) short bf16x8;   // 8 bf16 = 4 VGPR
typedef __attribute__((ext_vector_type(4))) float f32x4;

#define DEV __device__ __forceinline__

DEV float b2f(u16 u){ return __uint_as_float(((u32)u)<<16); }
DEV u16 f2b(float f){ u32 x = __float_as_uint(f); x += 0x7fffu + ((x>>16)&1u); return (u16)(x>>16); }
DEV u32 pk2(float a, float b){
  u32 r;
  asm("v_cvt_pk_bf16_f32 %0, %1, %2" : "=v"(r) : "v"(a), "v"(b));
  return r;
}

DEV void gll16(const void* g, void* l){
  __builtin_amdgcn_global_load_lds((const __attribute__((address_space(1))) u32*)g,
                                   (__attribute__((address_space(3))) u32*)l, 16, 0, 0);
}

// token row -> (window, in-window index);  H=W=D=32, g=8
DEV void win_n(int r, int& win, int& n){
  int d_ = r & 31, w_ = (r>>5)&31, h_ = r>>10;
  win = ((h_>>3)<<4) | ((w_>>3)<<2) | (d_>>3);
  n   = ((h_&7)<<6)  | ((w_&7)<<3)  | (d_&7);
}
// window-order row -> token row
DEV int tok_of(int r){
  int win = r>>9, nn = r&511;
  int bh = win>>4, bw=(win>>2)&3, bd=win&3;
  int ih = nn>>6,  iw=(nn>>3)&7,  id=nn&7;
  return ((bh*8+ih)<<10) | ((bw*8+iw)<<5) | (bd*8+id);
}

// ---------------- small prep kernels ----------------

// all four weight transposes in one dispatch: dst bf16 [N][K] = transpose(src fp32 [K][N])
__global__ void wtrall_k(const float* __restrict__ qkv_w, const float* __restrict__ proj_w,
                         const float* __restrict__ fc1_w, const float* __restrict__ fc2_w,
                         u16* __restrict__ qkvT, u16* __restrict__ projT,
                         u16* __restrict__ fc1T, u16* __restrict__ fc2T){
  int f = blockIdx.x*256 + threadIdx.x;   // 786432 total
  const float* w; u16* wt; int g; bool k10 = false; int N;
  if (f < 196608)      { w=qkv_w;  wt=qkvT;  g=f;        N=768;  }
  else if (f < 262144) { w=proj_w; wt=projT; g=f-196608; N=256;  }
  else if (f < 524288) { w=fc1_w;  wt=fc1T;  g=f-262144; N=1024; }
  else                 { w=fc2_w;  wt=fc2T;  g=f-524288; N=256;  k10=true; }
  int n = k10 ? (g>>10) : (g>>8);
  int k = k10 ? (g&1023) : (g&255);
  wt[g] = f2b(w[(size_t)k*N + n]);
}

__global__ void conv_k(const float* __restrict__ x, u16* __restrict__ o, int n4){
  int stride = gridDim.x*blockDim.x;
  for (int i = blockIdx.x*blockDim.x + threadIdx.x; i < n4; i += stride){
    const float4 v = *(const float4*)(x + (size_t)i*4);
    u32 lo = (u32)f2b(v.x) | ((u32)f2b(v.y)<<16);
    u32 hi = (u32)f2b(v.z) | ((u32)f2b(v.w)<<16);
    *(uint2*)(o + (size_t)i*4) = make_uint2(lo, hi);
  }
}

// LayerNorm over 256 cols, one wave per row, writes bf16
__global__ __launch_bounds__(256)
void ln_k(const float* __restrict__ x, const float* __restrict__ g,
          const float* __restrict__ b, u16* __restrict__ out){
  int row  = blockIdx.x*4 + (threadIdx.x>>6);
  int lane = threadIdx.x & 63;
  const float4 v = *(const float4*)(x + (size_t)row*256 + lane*4);
  float s = v.x+v.y+v.z+v.w;
  #pragma unroll
  for (int m=1;m<64;m<<=1) s += __shfl_xor(s, m);
  float mean = s * (1.0f/256.0f);
  float d0=v.x-mean,d1=v.y-mean,d2=v.z-mean,d3=v.w-mean;
  float q = d0*d0+d1*d1+d2*d2+d3*d3;
  #pragma unroll
  for (int m=1;m<64;m<<=1) q += __shfl_xor(q, m);
  float rs = rsqrtf(q*(1.0f/256.0f) + 1e-5f);
  const float4 gg = *(const float4*)(g + lane*4);
  const float4 bb = *(const float4*)(b + lane*4);
  u32 lo = (u32)f2b(d0*rs*gg.x+bb.x) | ((u32)f2b(d1*rs*gg.y+bb.y)<<16);
  u32 hi = (u32)f2b(d2*rs*gg.z+bb.z) | ((u32)f2b(d3*rs*gg.w+bb.w)<<16);
  *(uint2*)(out + (size_t)row*256 + lane*4) = make_uint2(lo,hi);
}

// position-bias MLP: one thread per table row (3375 rows); emits bf16 per-head tables
// scaled by log2(e) so attention softmax can run in exp2 domain.
template<int NOUT>
DEV void pstage(float* v, const float* g, const float* b, const float* W, const float* bb){
  float m = 0.f;
  #pragma unroll
  for (int i=0;i<16;i++) m += v[i];
  m *= 0.0625f;
  float q = 0.f;
  #pragma unroll
  for (int i=0;i<16;i++){ float d=v[i]-m; q += d*d; }
  float rs = rsqrtf(q*0.0625f + 1e-5f);
  float u[16];
  #pragma unroll
  for (int i=0;i<16;i++){ float t = (v[i]-m)*rs*g[i] + b[i]; u[i] = t>0.f?t:0.f; }
  #pragma unroll
  for (int o=0;o<NOUT;o++){
    float s = bb[o];
    #pragma unroll
    for (int kk=0;kk<16;kk++) s += u[kk]*W[kk*NOUT+o];
    v[o] = s;
  }
}

__global__ void posmlp_k(const float* pp_w, const float* pp_b,
                         const float* g1, const float* b1, const float* w1, const float* bb1,
                         const float* g2, const float* b2, const float* w2, const float* bb2,
                         const float* g3, const float* b3, const float* w3, const float* bb3,
                         u16* __restrict__ posb){
  int i = blockIdx.x*256 + threadIdx.x;
  if (i >= 3375) return;
  int t = i;
  int bd = t % 15; t /= 15;
  int bw = t % 15; t /= 15;
  int bh = t;
  float fh = (float)(bh-7), fw = (float)(bw-7), fd = (float)(bd-7);
  float v[16];
  #pragma unroll
  for (int o=0;o<16;o++) v[o] = fh*pp_w[o] + fw*pp_w[16+o] + fd*pp_w[32+o] + pp_b[o];
  pstage<16>(v, g1,b1,w1,bb1);
  pstage<16>(v, g2,b2,w2,bb2);
  pstage<8> (v, g3,b3,w3,bb3);
  #pragma unroll
  for (int h=0;h<8;h++) posb[(size_t)h*3376 + i] = f2b(v[h] * 1.4426950408889634f);
}

// ---------------- GEMM params ----------------
struct GemmP {
  const u16* A; const u16* Bt;
  int K;
  const float* bvec;
  float scale;
  const float* add32;
  float* out32;
  u16* out16;
  u16* out16b;
};

// shared epilogue: D layout col=lane&15, row=(lane>>4)*4+v  [verified m89]
template<int MODE>
DEV void epi(const GemmP& p, int r, int c, float val){
  if constexpr (MODE==0){           // Q: (val+b)*scale -> Q[win*8+h][n][d]
    float qv = (val + p.bvec[c]) * p.scale;
    int win, n; win_n(r, win, n);
    int hh = c>>5, dd = c&31;
    p.out16[((size_t)((win*8+hh)*512 + n)<<5) + dd] = f2b(qv);
  } else if constexpr (MODE==1){    // K (c<256) / V (c>=256), MFMA fragment layout
    float ov = val + p.bvec[c];
    int win, n; win_n(r, win, n);
    int cc = c & 255;
    int hh = cc>>5, dd = cc&31;
    size_t base = (size_t)(win*8+hh)*16384;
    if (c < 256){
      int nc = n>>4, ln2 = ((dd>>3)<<4)|(n&15), jj = dd&7;
      p.out16[base + (size_t)(nc*64+ln2)*8 + jj] = f2b(ov);
    } else {
      int fi = ((n>>5)<<1) | (dd>>4);
      int ln2 = (((n>>3)&3)<<4)|(dd&15), jj = n&7;
      p.out16b[base + (size_t)(fi*64+ln2)*8 + jj] = f2b(ov);
    }
  } else if constexpr (MODE==2){    // proj + x residual, window row -> token row
    int l = tok_of(r);
    size_t o = (size_t)l*256 + c;
    p.out32[o] = val + p.bvec[c] + p.add32[o];
  } else if constexpr (MODE==3){    // fc1 + exact GELU
    float u = val + p.bvec[c];
    float ge = 0.5f*u*(1.0f + erff(u*0.70710678118654752f));
    p.out16[(size_t)r*1024 + c] = f2b(ge);
  } else {                          // fc2 + residual -> fp32 out
    size_t o = (size_t)r*256 + c;
    p.out32[o] = val + p.bvec[c] + p.add32[o];
  }
}

// ---------------- full-K (K=256) GEMM: whole panels in LDS, one barrier, no inner syncs ----------
// 128x128 tile, 512 threads (8 waves, 2M x 4N), LDS 128 KB (1 block/CU).
// XOR swizzle on staging SOURCE + ds_read addr (involution) -> <=2-way conflicts.
template<int MODE>
__global__ __launch_bounds__(512)
void gemm256_k(GemmP p){
  __shared__ u16 lA[8][4096];   // [t][128 row][32 k] per tile, 8 KB each
  __shared__ u16 lB[8][4096];
  const int tid = threadIdx.x;
  const int wid = tid>>6, lane = tid&63;
  const int lr = lane&15, lg = lane>>4;
  const int m0 = blockIdx.x*128, n0 = blockIdx.y*128;
  const int wm = (wid>>2)*64, wn = (wid&3)*32;
  const f32x4 z4 = {0.f,0.f,0.f,0.f};

  // stage full A (64 KB) + B (64 KB) panels
  #pragma unroll
  for (int it=0; it<8; ++it){
    int off = it*8192 + tid*16;          // byte offset, linear LDS dest
    int t   = off>>13;
    int row = (off>>6)&127;
    int s   = (off>>4)&3;
    int kc  = s ^ ((row>>1)&3);          // inverse-swizzled source k-chunk
    const u16* ga;
    if constexpr (MODE==2){
      int rr = m0+row;                   // A = attnF [win*8+h][512 n][32 d]; t == head
      ga = p.A + ((size_t)((rr>>9)*8 + t)*512 + (rr&511))*32 + kc*8;
    } else {
      ga = p.A + (size_t)(m0+row)*256 + t*32 + kc*8;
    }
    gll16(ga, (char*)lA + off);
    gll16(p.Bt + (size_t)(n0+row)*256 + t*32 + kc*8, (char*)lB + off);
  }
  __syncthreads();

  f32x4 acc[4][2];
  #pragma unroll
  for (int i=0;i<4;i++){ acc[i][0]=z4; acc[i][1]=z4; }

  #pragma unroll
  for (int t=0;t<8;t++){
    bf16x8 af[4], bfr[2];
    #pragma unroll
    for (int i=0;i<4;i++){
      int row = wm + i*16 + lr;
      af[i] = *(const bf16x8*)((const char*)lA + t*8192 + row*64 + ((lg ^ ((row>>1)&3))<<4));
    }
    #pragma unroll
    for (int j=0;j<2;j++){
      int row = wn + j*16 + lr;
      bfr[j] = *(const bf16x8*)((const char*)lB + t*8192 + row*64 + ((lg ^ ((row>>1)&3))<<4));
    }
    #pragma unroll
    for (int i=0;i<4;i++)
      #pragma unroll
      for (int j=0;j<2;j++)
        acc[i][j] = __builtin_amdgcn_mfma_f32_16x16x32_bf16(af[i], bfr[j], acc[i][j], 0,0,0);
  }

  #pragma unroll
  for (int i=0;i<4;i++)
    #pragma unroll
    for (int j=0;j<2;j++)
      #pragma unroll
      for (int v=0;v<4;v++)
        epi<MODE>(p, m0 + wm + i*16 + lg*4 + v, n0 + wn + j*16 + lr, acc[i][j][v]);
}

// ---------------- K=1024 GEMM (fc2): m97-style double-buffered ----------------
template<int MODE>
__global__ __launch_bounds__(256)
void gemm_k(GemmP p){
  __shared__ u16 lA[2][4096];
  __shared__ u16 lB[2][4096];
  const int tid = threadIdx.x;
  const int wid = tid>>6, lane = tid&63;
  const int lr = lane&15, lg = lane>>4;
  const int m0 = blockIdx.x*128, n0 = blockIdx.y*128;
  const int K = p.K;
  const int nt = K>>5;
  const int wm = (wid>>1)*64, wn = (wid&1)*64;
  const f32x4 z4 = {0.f,0.f,0.f,0.f};

  f32x4 acc[4][4];
  #pragma unroll
  for (int i=0;i<4;i++)
    #pragma unroll
    for (int j=0;j<4;j++) acc[i][j] = z4;

  #pragma unroll
  for (int r=0;r<2;r++){
    int off = (r*256 + tid)*16;
    int row = off>>6, kc = (off&63)>>1;
    gll16(p.A  + (size_t)(m0+row)*K + kc, (char*)lA[0] + off);
    gll16(p.Bt + (size_t)(n0+row)*K + kc, (char*)lB[0] + off);
  }
  __syncthreads();
  int cur = 0;
  for (int t=0; t<nt; ++t){
    if (t+1 < nt){
      int k0 = (t+1)<<5;
      #pragma unroll
      for (int r=0;r<2;r++){
        int off = (r*256 + tid)*16;
        int row = off>>6, kc = (off&63)>>1;
        gll16(p.A  + (size_t)(m0+row)*K + k0 + kc, (char*)lA[cur^1] + off);
        gll16(p.Bt + (size_t)(n0+row)*K + k0 + kc, (char*)lB[cur^1] + off);
      }
    }
    bf16x8 af[4], bfr[4];
    #pragma unroll
    for (int i=0;i<4;i++){
      af[i]  = *(const bf16x8*)&lA[cur][(wm + i*16 + lr)*32 + lg*8];
      bfr[i] = *(const bf16x8*)&lB[cur][(wn + i*16 + lr)*32 + lg*8];
    }
    #pragma unroll
    for (int i=0;i<4;i++)
      #pragma unroll
      for (int j=0;j<4;j++)
        acc[i][j] = __builtin_amdgcn_mfma_f32_16x16x32_bf16(af[i], bfr[j], acc[i][j], 0,0,0);
    __syncthreads();
    cur ^= 1;
  }

  #pragma unroll
  for (int i=0;i<4;i++)
    #pragma unroll
    for (int j=0;j<4;j++)
      #pragma unroll
      for (int v=0;v<4;v++)
        epi<MODE>(p, m0 + wm + i*16 + lg*4 + v, n0 + wn + j*16 + lr, acc[i][j][v]);
}

// ---------------- attention: one block per (window, head), 8 waves, flash 2-phase ----------------
// exp2-domain softmax (log2e pre-folded into Q scale and pos table); defer-rescale (T13);
// s_setprio around MFMA clusters (T5).
__global__ __launch_bounds__(512, 4)
void attn_k(const u16* __restrict__ Q, const u16* __restrict__ Kf,
            const u16* __restrict__ Vf, const u16* __restrict__ posb,
            u16* __restrict__ outF){
  __shared__ u16 lK[16384];      // 32 frags x 1KB, fragment order
  __shared__ u16 lV[16384];      // 32 frags x 1KB (16 kc x 2 dblk)
  __shared__ u16 lP[2][3392];    // pos table, copy1 shifted by +1 element (parity align)
  const int bid = blockIdx.x;
  const int hh = bid&7;
  const int tid = threadIdx.x, wid = tid>>6, lane = tid&63;
  const int lr = lane&15, lg = lane>>4;
  const u16* Kb = Kf + (size_t)bid*16384;
  const u16* Vb = Vf + (size_t)bid*16384;
  const u16* Qb = Q  + (size_t)bid*16384;
  #pragma unroll
  for (int r=0;r<4;r++){
    int off = (r*512 + tid)*16;
    gll16((const char*)Kb + off, (char*)lK + off);
    gll16((const char*)Vb + off, (char*)lV + off);
  }
  const u16* ptab = posb + (size_t)hh*3376;
  for (int t=tid; t<3375; t+=512){
    u16 u = ptab[t];
    lP[0][t]   = u;
    lP[1][t+1] = u;
  }
  __syncthreads();
  const f32x4 z4 = {0.f,0.f,0.f,0.f};

  for (int ch=0; ch<4; ++ch){
    const int r0 = wid*64 + ch*16;
    const int q  = r0 + lr;
    // bias index base: idx(nc,v) = Ab - (nc>>2)*225 - (nc&3)*30 - v
    const int Ab = (q>>6)*225 + ((q>>3)&7)*15 + (q&7) + 1687 - (lg>>1)*15 - (lg&1)*4;
    bf16x8 qf = *(const bf16x8*)(Qb + (size_t)q*32 + lg*8);
    f32x4 o0 = z4, o1 = z4;
    float m = -3.0e38f, s = 0.f;
    #pragma unroll
    for (int ph=0; ph<2; ++ph){
      // S^T frags for this half: sf[i][v] = S[q][n=(ph*16+i)*16+lg*4+v]  (exp2 domain)
      f32x4 sf[16];
      __builtin_amdgcn_s_setprio(1);
      #pragma unroll
      for (int i=0;i<16;i++){
        int nc = ph*16 + i;
        bf16x8 kf = *(const bf16x8*)&lK[(nc*64 + lane)*8];
        sf[i] = __builtin_amdgcn_mfma_f32_16x16x32_bf16(kf, qf, z4, 0,0,0);
      }
      __builtin_amdgcn_s_setprio(0);
      // + bias via LDS gather: pos[idx0-3..idx0] = two aligned b32 from parity copy
      #pragma unroll
      for (int i=0;i<16;i++){
        int nc = ph*16 + i;
        int idx0 = Ab - (nc>>2)*225 - (nc&3)*30;
        int par = (idx0+1)&1;                       // parity of e1=idx0-3
        const char* bp = (const char*)lP + ((idx0-3)<<1) + par*6786;
        u32 u1 = *(const u32*)(bp);                 // (pos[idx0-3], pos[idx0-2])
        u32 u2 = *(const u32*)(bp + 4);             // (pos[idx0-1], pos[idx0])
        sf[i][3] += __uint_as_float(u1<<16);
        sf[i][2] += __uint_as_float(u1 & 0xffff0000u);
        sf[i][1] += __uint_as_float(u2<<16);
        sf[i][0] += __uint_as_float(u2 & 0xffff0000u);
      }
      // row max of this half (row q per lane; combine lg groups)
      float pm = -3.0e38f;
      #pragma unroll
      for (int i=0;i<16;i++)
        pm = fmaxf(pm, fmaxf(fmaxf(sf[i][0],sf[i][1]), fmaxf(sf[i][2],sf[i][3])));
      pm = fmaxf(pm, __shfl_xor(pm,16));
      pm = fmaxf(pm, __shfl_xor(pm,32));
      if (ph == 0){
        m = pm;
      } else if (!__all(pm <= m + 8.0f)){  // T13: skip rescale when max barely grew
        float mn = fmaxf(m, pm);
        float f = exp2f(m - mn);
        s *= f;
        float f0 = __shfl(f, lg*4+0), f1 = __shfl(f, lg*4+1);
        float f2 = __shfl(f, lg*4+2), f3 = __shfl(f, lg*4+3);
        o0[0]*=f0; o0[1]*=f1; o0[2]*=f2; o0[3]*=f3;
        o1[0]*=f0; o1[1]*=f1; o1[2]*=f2; o1[3]*=f3;
        m = mn;
      }
      float ls = 0.f;
      #pragma unroll
      for (int i=0;i<16;i++){
        #pragma unroll
        for (int v=0;v<4;v++){ float e = exp2f(sf[i][v]-m); sf[i][v]=e; ls+=e; }
      }
      ls += __shfl_xor(ls,16);
      ls += __shfl_xor(ls,32);
      s += ls;
      // PV over this half's 8 kc blocks
      #pragma unroll
      for (int kc=0;kc<8;kc++){
        u32 a0 = pk2(sf[2*kc  ][0], sf[2*kc  ][1]);
        u32 a1 = pk2(sf[2*kc  ][2], sf[2*kc  ][3]);
        u32 b0 = pk2(sf[2*kc+1][0], sf[2*kc+1][1]);
        u32 b1 = pk2(sf[2*kc+1][2], sf[2*kc+1][3]);
        asm("v_permlane32_swap_b32 %0, %1" : "+v"(a0), "+v"(b0));
        asm("v_permlane16_swap_b32 %0, %1" : "+v"(a0), "+v"(b0));  // a0=T0, b0=T2
        asm("v_permlane32_swap_b32 %0, %1" : "+v"(a1), "+v"(b1));
        asm("v_permlane16_swap_b32 %0, %1" : "+v"(a1), "+v"(b1));  // a1=T1, b1=T3
        bf16x8 pf;
        ((u32*)&pf)[0]=a0; ((u32*)&pf)[1]=a1; ((u32*)&pf)[2]=b0; ((u32*)&pf)[3]=b1;
        int kcg = ph*8 + kc;
        bf16x8 v0 = *(const bf16x8*)&lV[(size_t)((kcg*2+0)*64 + lane)*8];
        bf16x8 v1 = *(const bf16x8*)&lV[(size_t)((kcg*2+1)*64 + lane)*8];
        __builtin_amdgcn_s_setprio(1);
        o0 = __builtin_amdgcn_mfma_f32_16x16x32_bf16(pf, v0, o0, 0,0,0);
        o1 = __builtin_amdgcn_mfma_f32_16x16x32_bf16(pf, v1, o1, 0,0,0);
        __builtin_amdgcn_s_setprio(0);
      }
    }
    #pragma unroll
    for (int v=0;v<4;v++){
      float inv = 1.0f / __shfl(s, lg*4+v);
      int n = r0 + lg*4 + v;
      size_t base = ((size_t)bid*512 + n)*32;
      outF[base + lr]      = f2b(o0[v]*inv);
      outF[base + 16 + lr] = f2b(o1[v]*inv);
    }
  }
}

// ---------------- host launch ----------------
extern "C" void kernel_launch(void* const* d_in, const int* in_sizes, int n_in,
                              void* d_out, int out_size, void* d_ws, size_t ws_size,
                              hipStream_t stream){
  const float* x      = (const float*)d_in[0];
  const float* y      = (const float*)d_in[1];
  const float* n1_g   = (const float*)d_in[2];
  const float* n1_b   = (const float*)d_in[3];
  const float* qkv_w  = (const float*)d_in[4];
  const float* qkv_b  = (const float*)d_in[5];
  const float* pp_w   = (const float*)d_in[6];
  const float* pp_b   = (const float*)d_in[7];
  const float* p1_lng = (const float*)d_in[8];
  const float* p1_lnb = (const float*)d_in[9];
  const float* p1_w   = (const float*)d_in[10];
  const float* p1_b   = (const float*)d_in[11];
  const float* p2_lng = (const float*)d_in[12];
  const float* p2_lnb = (const float*)d_in[13];
  const float* p2_w   = (const float*)d_in[14];
  const float* p2_b   = (const float*)d_in[15];
  const float* p3_lng = (const float*)d_in[16];
  const float* p3_lnb = (const float*)d_in[17];
  const float* p3_w   = (const float*)d_in[18];
  const float* p3_b   = (const float*)d_in[19];
  const float* proj_w = (const float*)d_in[20];
  const float* proj_b = (const float*)d_in[21];
  const float* n2_g   = (const float*)d_in[22];
  const float* n2_b   = (const float*)d_in[23];
  const float* fc1_w  = (const float*)d_in[24];
  const float* fc1_b  = (const float*)d_in[25];
  const float* fc2_w  = (const float*)d_in[26];
  const float* fc2_b  = (const float*)d_in[27];
  float* out = (float*)d_out;
  char* ws = (char*)d_ws;

  // workspace layout (bytes)
  u16*   qkvT  = (u16*)  (ws + 0);          // [768][256] bf16
  u16*   projT = (u16*)  (ws + 393216);     // [256][256]
  u16*   fc1T  = (u16*)  (ws + 524288);     // [1024][256]
  u16*   fc2T  = (u16*)  (ws + 1048576);    // [256][1024]
  u16*   posb  = (u16*)  (ws + 1572864);    // [8][3376] bf16 per-head pos tables (x log2e)
  u16*   xn    = (u16*)  (ws + 5898240);    // [32768][256]
  u16*   yb    = (u16*)  (ws + 22675456);
  u16*   Qb    = (u16*)  (ws + 39452672);   // [512 bh][512 n][32 d]
  u16*   Kfb   = (u16*)  (ws + 56229888);   // [512 bh][32 frag][64 lane][8]
  u16*   Vfb   = (u16*)  (ws + 73007104);   // [512 bh][32 frag][64 lane][8]
  u16*   attnF = (u16*)  (ws + 89784320);   // [512 bh][512 n][32 d] block-contiguous
  float* xres  = (float*)(ws + 106561536);  // [32768][256] fp32   (end 140,115,968)
  u16*   hbuf  = xn;     // alias: MLP hidden [32768][1024], xn/yb/Qb/Kfb dead by then
  u16*   x2n   = attnF;  // alias: LN2 output, attnF dead after proj

  wtrall_k<<<3072,256,0,stream>>>(qkv_w, proj_w, fc1_w, fc2_w, qkvT, projT, fc1T, fc2T);
  posmlp_k<<<14,256,0,stream>>>(pp_w, pp_b,
                                p1_lng,p1_lnb,p1_w,p1_b,
                                p2_lng,p2_lnb,p2_w,p2_b,
                                p3_lng,p3_lnb,p3_w,p3_b, posb);
  ln_k<<<8192,256,0,stream>>>(x, n1_g, n1_b, xn);
  conv_k<<<2048,256,0,stream>>>(y, yb, 2097152);

  GemmP pq; pq.A=xn; pq.Bt=qkvT; pq.K=256; pq.bvec=qkv_b;
  pq.scale=0.17677669529663687f*1.4426950408889634f;  // hd^-0.5 * log2(e)
  pq.add32=nullptr; pq.out32=nullptr; pq.out16=Qb; pq.out16b=nullptr;
  gemm256_k<0><<<dim3(256,2),512,0,stream>>>(pq);

  GemmP pkv; pkv.A=yb; pkv.Bt=qkvT + 256*256; pkv.K=256; pkv.bvec=qkv_b + 256;
  pkv.scale=1.f; pkv.add32=nullptr; pkv.out32=nullptr; pkv.out16=Kfb; pkv.out16b=Vfb;
  gemm256_k<1><<<dim3(256,4),512,0,stream>>>(pkv);

  attn_k<<<512,512,0,stream>>>(Qb, Kfb, Vfb, posb, attnF);

  GemmP pp; pp.A=attnF; pp.Bt=projT; pp.K=256; pp.bvec=proj_b;
  pp.scale=1.f; pp.add32=x; pp.out32=xres; pp.out16=nullptr; pp.out16b=nullptr;
  gemm256_k<2><<<dim3(256,2),512,0,stream>>>(pp);

  ln_k<<<8192,256,0,stream>>>(xres, n2_g, n2_b, x2n);

  GemmP pf1; pf1.A=x2n; pf1.Bt=fc1T; pf1.K=256; pf1.bvec=fc1_b;
  pf1.scale=1.f; pf1.add32=nullptr; pf1.out32=nullptr; pf1.out16=hbuf; pf1.out16b=nullptr;
  gemm256_k<3><<<dim3(256,8),512,0,stream>>>(pf1);

  GemmP pf2; pf2.A=hbuf; pf2.Bt=fc2T; pf2.K=1024; pf2.bvec=fc2_b;
  pf2.scale=1.f; pf2.add32=xres; pf2.out32=out; pf2.out16=nullptr; pf2.out16b=nullptr;
  gemm_k<4><<<dim3(256,2),256,0,stream>>>(pf2);
}

// Round 6
// 291.606 us; speedup vs baseline: 1.4087x; 1.0488x over previous
//
#include <hip/hip_runtime.h>
#include <cstdint>
#include <cstddef>

typedef unsigned int u32;
typedef unsigned short u16;
typedef __attribute__((ext_vector_type(8))) short bf16x8;   // 8 bf16 = 4 VGPR
typedef __attribute__((ext_vector_type(4))) float f32x4;

#define DEV __device__ __forceinline__

DEV float b2f(u16 u){ return __uint_as_float(((u32)u)<<16); }
DEV u16 f2b(float f){ u32 x = __float_as_uint(f); x += 0x7fffu + ((x>>16)&1u); return (u16)(x>>16); }
DEV u32 pk2(float a, float b){
  u32 r;
  asm("v_cvt_pk_bf16_f32 %0, %1, %2" : "=v"(r) : "v"(a), "v"(b));
  return r;
}

DEV void gll16(const void* g, void* l){
  __builtin_amdgcn_global_load_lds((const __attribute__((address_space(1))) u32*)g,
                                   (__attribute__((address_space(3))) u32*)l, 16, 0, 0);
}

// token row -> (window, in-window index);  H=W=D=32, g=8
DEV void win_n(int r, int& win, int& n){
  int d_ = r & 31, w_ = (r>>5)&31, h_ = r>>10;
  win = ((h_>>3)<<4) | ((w_>>3)<<2) | (d_>>3);
  n   = ((h_&7)<<6)  | ((w_&7)<<3)  | (d_&7);
}
// window-order row -> token row
DEV int tok_of(int r){
  int win = r>>9, nn = r&511;
  int bh = win>>4, bw=(win>>2)&3, bd=win&3;
  int ih = nn>>6,  iw=(nn>>3)&7,  id=nn&7;
  return ((bh*8+ih)<<10) | ((bw*8+iw)<<5) | (bd*8+id);
}

// ---------------- small prep kernels ----------------

// all four weight transposes in one dispatch: dst bf16 [N][K] = transpose(src fp32 [K][N])
__global__ void wtrall_k(const float* __restrict__ qkv_w, const float* __restrict__ proj_w,
                         const float* __restrict__ fc1_w, const float* __restrict__ fc2_w,
                         u16* __restrict__ qkvT, u16* __restrict__ projT,
                         u16* __restrict__ fc1T, u16* __restrict__ fc2T){
  int f = blockIdx.x*256 + threadIdx.x;   // 786432 total
  const float* w; u16* wt; int g; bool k10 = false; int N;
  if (f < 196608)      { w=qkv_w;  wt=qkvT;  g=f;        N=768;  }
  else if (f < 262144) { w=proj_w; wt=projT; g=f-196608; N=256;  }
  else if (f < 524288) { w=fc1_w;  wt=fc1T;  g=f-262144; N=1024; }
  else                 { w=fc2_w;  wt=fc2T;  g=f-524288; N=256;  k10=true; }
  int n = k10 ? (g>>10) : (g>>8);
  int k = k10 ? (g&1023) : (g&255);
  wt[g] = f2b(w[(size_t)k*N + n]);
}

__global__ void conv_k(const float* __restrict__ x, u16* __restrict__ o, int n4){
  int stride = gridDim.x*blockDim.x;
  for (int i = blockIdx.x*blockDim.x + threadIdx.x; i < n4; i += stride){
    const float4 v = *(const float4*)(x + (size_t)i*4);
    u32 lo = (u32)f2b(v.x) | ((u32)f2b(v.y)<<16);
    u32 hi = (u32)f2b(v.z) | ((u32)f2b(v.w)<<16);
    *(uint2*)(o + (size_t)i*4) = make_uint2(lo, hi);
  }
}

// LayerNorm over 256 cols, one wave per row, writes bf16
__global__ __launch_bounds__(256)
void ln_k(const float* __restrict__ x, const float* __restrict__ g,
          const float* __restrict__ b, u16* __restrict__ out){
  int row  = blockIdx.x*4 + (threadIdx.x>>6);
  int lane = threadIdx.x & 63;
  const float4 v = *(const float4*)(x + (size_t)row*256 + lane*4);
  float s = v.x+v.y+v.z+v.w;
  #pragma unroll
  for (int m=1;m<64;m<<=1) s += __shfl_xor(s, m);
  float mean = s * (1.0f/256.0f);
  float d0=v.x-mean,d1=v.y-mean,d2=v.z-mean,d3=v.w-mean;
  float q = d0*d0+d1*d1+d2*d2+d3*d3;
  #pragma unroll
  for (int m=1;m<64;m<<=1) q += __shfl_xor(q, m);
  float rs = rsqrtf(q*(1.0f/256.0f) + 1e-5f);
  const float4 gg = *(const float4*)(g + lane*4);
  const float4 bb = *(const float4*)(b + lane*4);
  u32 lo = (u32)f2b(d0*rs*gg.x+bb.x) | ((u32)f2b(d1*rs*gg.y+bb.y)<<16);
  u32 hi = (u32)f2b(d2*rs*gg.z+bb.z) | ((u32)f2b(d3*rs*gg.w+bb.w)<<16);
  *(uint2*)(out + (size_t)row*256 + lane*4) = make_uint2(lo,hi);
}

// position-bias MLP: one thread per table row (3375 rows); emits bf16 per-head tables
// scaled by log2(e) so attention softmax can run in exp2 domain.
template<int NOUT>
DEV void pstage(float* v, const float* g, const float* b, const float* W, const float* bb){
  float m = 0.f;
  #pragma unroll
  for (int i=0;i<16;i++) m += v[i];
  m *= 0.0625f;
  float q = 0.f;
  #pragma unroll
  for (int i=0;i<16;i++){ float d=v[i]-m; q += d*d; }
  float rs = rsqrtf(q*0.0625f + 1e-5f);
  float u[16];
  #pragma unroll
  for (int i=0;i<16;i++){ float t = (v[i]-m)*rs*g[i] + b[i]; u[i] = t>0.f?t:0.f; }
  #pragma unroll
  for (int o=0;o<NOUT;o++){
    float s = bb[o];
    #pragma unroll
    for (int kk=0;kk<16;kk++) s += u[kk]*W[kk*NOUT+o];
    v[o] = s;
  }
}

__global__ void posmlp_k(const float* pp_w, const float* pp_b,
                         const float* g1, const float* b1, const float* w1, const float* bb1,
                         const float* g2, const float* b2, const float* w2, const float* bb2,
                         const float* g3, const float* b3, const float* w3, const float* bb3,
                         u16* __restrict__ posb){
  int i = blockIdx.x*256 + threadIdx.x;
  if (i >= 3375) return;
  int t = i;
  int bd = t % 15; t /= 15;
  int bw = t % 15; t /= 15;
  int bh = t;
  float fh = (float)(bh-7), fw = (float)(bw-7), fd = (float)(bd-7);
  float v[16];
  #pragma unroll
  for (int o=0;o<16;o++) v[o] = fh*pp_w[o] + fw*pp_w[16+o] + fd*pp_w[32+o] + pp_b[o];
  pstage<16>(v, g1,b1,w1,bb1);
  pstage<16>(v, g2,b2,w2,bb2);
  pstage<8> (v, g3,b3,w3,bb3);
  #pragma unroll
  for (int h=0;h<8;h++) posb[(size_t)h*3376 + i] = f2b(v[h] * 1.4426950408889634f);
}

// ---------------- GEMM params ----------------
struct GemmP {
  const u16* A; const u16* Bt;
  int K;
  const float* bvec;
  float scale;
  const float* add32;
  float* out32;
  u16* out16;
  u16* out16b;
};

// shared epilogue: D layout col=lane&15, row=(lane>>4)*4+v  [verified m89]
template<int MODE>
DEV void epi(const GemmP& p, int r, int c, float val){
  if constexpr (MODE==0){           // Q: (val+b)*scale -> Q[win*8+h][n][d]
    float qv = (val + p.bvec[c]) * p.scale;
    int win, n; win_n(r, win, n);
    int hh = c>>5, dd = c&31;
    p.out16[((size_t)((win*8+hh)*512 + n)<<5) + dd] = f2b(qv);
  } else if constexpr (MODE==1){    // K (c<256) / V (c>=256), MFMA fragment layout
    float ov = val + p.bvec[c];
    int win, n; win_n(r, win, n);
    int cc = c & 255;
    int hh = cc>>5, dd = cc&31;
    size_t base = (size_t)(win*8+hh)*16384;
    if (c < 256){
      int nc = n>>4, ln2 = ((dd>>3)<<4)|(n&15), jj = dd&7;
      p.out16[base + (size_t)(nc*64+ln2)*8 + jj] = f2b(ov);
    } else {
      int fi = ((n>>5)<<1) | (dd>>4);
      int ln2 = (((n>>3)&3)<<4)|(dd&15), jj = n&7;
      p.out16b[base + (size_t)(fi*64+ln2)*8 + jj] = f2b(ov);
    }
  } else if constexpr (MODE==2){    // proj + x residual, window row -> token row
    int l = tok_of(r);
    size_t o = (size_t)l*256 + c;
    p.out32[o] = val + p.bvec[c] + p.add32[o];
  } else if constexpr (MODE==3){    // fc1 + exact GELU
    float u = val + p.bvec[c];
    float ge = 0.5f*u*(1.0f + erff(u*0.70710678118654752f));
    p.out16[(size_t)r*1024 + c] = f2b(ge);
  } else {                          // fc2 + residual -> fp32 out
    size_t o = (size_t)r*256 + c;
    p.out32[o] = val + p.bvec[c] + p.add32[o];
  }
}

// ---------------- full-K (K=256) GEMM: whole panels in LDS, one barrier, no inner syncs ----------
// 128x128 tile, 512 threads (8 waves, 2M x 4N), LDS 128 KB (1 block/CU).
// grid: x = n-block (fast), y = m-block -> consecutive blocks share A panel (L2-hot).
template<int MODE>
__global__ __launch_bounds__(512)
void gemm256_k(GemmP p){
  __shared__ u16 lA[8][4096];   // [t][128 row][32 k] per tile, 8 KB each
  __shared__ u16 lB[8][4096];
  const int tid = threadIdx.x;
  const int wid = tid>>6, lane = tid&63;
  const int lr = lane&15, lg = lane>>4;
  const int m0 = blockIdx.y*128, n0 = blockIdx.x*128;
  const int wm = (wid>>2)*64, wn = (wid&3)*32;
  const f32x4 z4 = {0.f,0.f,0.f,0.f};

  // stage full A (64 KB) + B (64 KB) panels
  #pragma unroll
  for (int it=0; it<8; ++it){
    int off = it*8192 + tid*16;          // byte offset, linear LDS dest
    int t   = off>>13;
    int row = (off>>6)&127;
    int s   = (off>>4)&3;
    int kc  = s ^ ((row>>1)&3);          // inverse-swizzled source k-chunk
    const u16* ga;
    if constexpr (MODE==2){
      int rr = m0+row;                   // A = attnF [win*8+h][512 n][32 d]; t == head
      ga = p.A + ((size_t)((rr>>9)*8 + t)*512 + (rr&511))*32 + kc*8;
    } else {
      ga = p.A + (size_t)(m0+row)*256 + t*32 + kc*8;
    }
    gll16(ga, (char*)lA + off);
    gll16(p.Bt + (size_t)(n0+row)*256 + t*32 + kc*8, (char*)lB + off);
  }
  __syncthreads();

  f32x4 acc[4][2];
  #pragma unroll
  for (int i=0;i<4;i++){ acc[i][0]=z4; acc[i][1]=z4; }

  #pragma unroll
  for (int t=0;t<8;t++){
    bf16x8 af[4], bfr[2];
    #pragma unroll
    for (int i=0;i<4;i++){
      int row = wm + i*16 + lr;
      af[i] = *(const bf16x8*)((const char*)lA + t*8192 + row*64 + ((lg ^ ((row>>1)&3))<<4));
    }
    #pragma unroll
    for (int j=0;j<2;j++){
      int row = wn + j*16 + lr;
      bfr[j] = *(const bf16x8*)((const char*)lB + t*8192 + row*64 + ((lg ^ ((row>>1)&3))<<4));
    }
    #pragma unroll
    for (int i=0;i<4;i++)
      #pragma unroll
      for (int j=0;j<2;j++)
        acc[i][j] = __builtin_amdgcn_mfma_f32_16x16x32_bf16(af[i], bfr[j], acc[i][j], 0,0,0);
  }

  #pragma unroll
  for (int i=0;i<4;i++)
    #pragma unroll
    for (int j=0;j<2;j++)
      #pragma unroll
      for (int v=0;v<4;v++)
        epi<MODE>(p, m0 + wm + i*16 + lg*4 + v, n0 + wn + j*16 + lr, acc[i][j][v]);
}

// ---------------- K=1024 GEMM (fc2): m97-style double-buffered ----------------
// grid: x = n-block (fast), y = m-block
template<int MODE>
__global__ __launch_bounds__(256)
void gemm_k(GemmP p){
  __shared__ u16 lA[2][4096];
  __shared__ u16 lB[2][4096];
  const int tid = threadIdx.x;
  const int wid = tid>>6, lane = tid&63;
  const int lr = lane&15, lg = lane>>4;
  const int m0 = blockIdx.y*128, n0 = blockIdx.x*128;
  const int K = p.K;
  const int nt = K>>5;
  const int wm = (wid>>1)*64, wn = (wid&1)*64;
  const f32x4 z4 = {0.f,0.f,0.f,0.f};

  f32x4 acc[4][4];
  #pragma unroll
  for (int i=0;i<4;i++)
    #pragma unroll
    for (int j=0;j<4;j++) acc[i][j] = z4;

  #pragma unroll
  for (int r=0;r<2;r++){
    int off = (r*256 + tid)*16;
    int row = off>>6, kc = (off&63)>>1;
    gll16(p.A  + (size_t)(m0+row)*K + kc, (char*)lA[0] + off);
    gll16(p.Bt + (size_t)(n0+row)*K + kc, (char*)lB[0] + off);
  }
  __syncthreads();
  int cur = 0;
  for (int t=0; t<nt; ++t){
    if (t+1 < nt){
      int k0 = (t+1)<<5;
      #pragma unroll
      for (int r=0;r<2;r++){
        int off = (r*256 + tid)*16;
        int row = off>>6, kc = (off&63)>>1;
        gll16(p.A  + (size_t)(m0+row)*K + k0 + kc, (char*)lA[cur^1] + off);
        gll16(p.Bt + (size_t)(n0+row)*K + k0 + kc, (char*)lB[cur^1] + off);
      }
    }
    bf16x8 af[4], bfr[4];
    #pragma unroll
    for (int i=0;i<4;i++){
      af[i]  = *(const bf16x8*)&lA[cur][(wm + i*16 + lr)*32 + lg*8];
      bfr[i] = *(const bf16x8*)&lB[cur][(wn + i*16 + lr)*32 + lg*8];
    }
    #pragma unroll
    for (int i=0;i<4;i++)
      #pragma unroll
      for (int j=0;j<4;j++)
        acc[i][j] = __builtin_amdgcn_mfma_f32_16x16x32_bf16(af[i], bfr[j], acc[i][j], 0,0,0);
    __syncthreads();
    cur ^= 1;
  }

  #pragma unroll
  for (int i=0;i<4;i++)
    #pragma unroll
    for (int j=0;j<4;j++)
      #pragma unroll
      for (int v=0;v<4;v++)
        epi<MODE>(p, m0 + wm + i*16 + lg*4 + v, n0 + wn + j*16 + lr, acc[i][j][v]);
}

// ---------------- attention: one block per (window, head), 8 waves, flash 2-phase ----------------
// exp2-domain softmax (log2e pre-folded into Q scale and pos table); defer-rescale (T13);
// s_setprio around MFMA clusters (T5).
// __launch_bounds__(512, 2): 2 blocks/CU min -> 128-VGPR budget; sf[16] etc (~115 regs)
// stay in arch VGPRs (the (512,4) variant capped at 64 VGPR -> AGPR/scratch churn).
__global__ __launch_bounds__(512, 2)
void attn_k(const u16* __restrict__ Q, const u16* __restrict__ Kf,
            const u16* __restrict__ Vf, const u16* __restrict__ posb,
            u16* __restrict__ outF){
  __shared__ u16 lK[16384];      // 32 frags x 1KB, fragment order
  __shared__ u16 lV[16384];      // 32 frags x 1KB (16 kc x 2 dblk)
  __shared__ u16 lP[2][3392];    // pos table, copy1 shifted by +1 element (parity align)
  const int bid = blockIdx.x;
  const int hh = bid&7;
  const int tid = threadIdx.x, wid = tid>>6, lane = tid&63;
  const int lr = lane&15, lg = lane>>4;
  const u16* Kb = Kf + (size_t)bid*16384;
  const u16* Vb = Vf + (size_t)bid*16384;
  const u16* Qb = Q  + (size_t)bid*16384;
  #pragma unroll
  for (int r=0;r<4;r++){
    int off = (r*512 + tid)*16;
    gll16((const char*)Kb + off, (char*)lK + off);
    gll16((const char*)Vb + off, (char*)lV + off);
  }
  const u16* ptab = posb + (size_t)hh*3376;
  for (int t=tid; t<3375; t+=512){
    u16 u = ptab[t];
    lP[0][t]   = u;
    lP[1][t+1] = u;
  }
  __syncthreads();
  const f32x4 z4 = {0.f,0.f,0.f,0.f};

  for (int ch=0; ch<4; ++ch){
    const int r0 = wid*64 + ch*16;
    const int q  = r0 + lr;
    // bias index base: idx(nc,v) = Ab - (nc>>2)*225 - (nc&3)*30 - v
    const int Ab = (q>>6)*225 + ((q>>3)&7)*15 + (q&7) + 1687 - (lg>>1)*15 - (lg&1)*4;
    bf16x8 qf = *(const bf16x8*)(Qb + (size_t)q*32 + lg*8);
    f32x4 o0 = z4, o1 = z4;
    float m = -3.0e38f, s = 0.f;
    #pragma unroll
    for (int ph=0; ph<2; ++ph){
      // S^T frags for this half: sf[i][v] = S[q][n=(ph*16+i)*16+lg*4+v]  (exp2 domain)
      f32x4 sf[16];
      __builtin_amdgcn_s_setprio(1);
      #pragma unroll
      for (int i=0;i<16;i++){
        int nc = ph*16 + i;
        bf16x8 kf = *(const bf16x8*)&lK[(nc*64 + lane)*8];
        sf[i] = __builtin_amdgcn_mfma_f32_16x16x32_bf16(kf, qf, z4, 0,0,0);
      }
      __builtin_amdgcn_s_setprio(0);
      // + bias via LDS gather: pos[idx0-3..idx0] = two aligned b32 from parity copy
      #pragma unroll
      for (int i=0;i<16;i++){
        int nc = ph*16 + i;
        int idx0 = Ab - (nc>>2)*225 - (nc&3)*30;
        int par = (idx0+1)&1;                       // parity of e1=idx0-3
        const char* bp = (const char*)lP + ((idx0-3)<<1) + par*6786;
        u32 u1 = *(const u32*)(bp);                 // (pos[idx0-3], pos[idx0-2])
        u32 u2 = *(const u32*)(bp + 4);             // (pos[idx0-1], pos[idx0])
        sf[i][3] += __uint_as_float(u1<<16);
        sf[i][2] += __uint_as_float(u1 & 0xffff0000u);
        sf[i][1] += __uint_as_float(u2<<16);
        sf[i][0] += __uint_as_float(u2 & 0xffff0000u);
      }
      // row max of this half (row q per lane; combine lg groups)
      float pm = -3.0e38f;
      #pragma unroll
      for (int i=0;i<16;i++)
        pm = fmaxf(pm, fmaxf(fmaxf(sf[i][0],sf[i][1]), fmaxf(sf[i][2],sf[i][3])));
      pm = fmaxf(pm, __shfl_xor(pm,16));
      pm = fmaxf(pm, __shfl_xor(pm,32));
      if (ph == 0){
        m = pm;
      } else if (!__all(pm <= m + 8.0f)){  // T13: skip rescale when max barely grew
        float mn = fmaxf(m, pm);
        float f = exp2f(m - mn);
        s *= f;
        float f0 = __shfl(f, lg*4+0), f1 = __shfl(f, lg*4+1);
        float f2 = __shfl(f, lg*4+2), f3 = __shfl(f, lg*4+3);
        o0[0]*=f0; o0[1]*=f1; o0[2]*=f2; o0[3]*=f3;
        o1[0]*=f0; o1[1]*=f1; o1[2]*=f2; o1[3]*=f3;
        m = mn;
      }
      float ls = 0.f;
      #pragma unroll
      for (int i=0;i<16;i++){
        #pragma unroll
        for (int v=0;v<4;v++){ float e = exp2f(sf[i][v]-m); sf[i][v]=e; ls+=e; }
      }
      ls += __shfl_xor(ls,16);
      ls += __shfl_xor(ls,32);
      s += ls;
      // PV over this half's 8 kc blocks
      #pragma unroll
      for (int kc=0;kc<8;kc++){
        u32 a0 = pk2(sf[2*kc  ][0], sf[2*kc  ][1]);
        u32 a1 = pk2(sf[2*kc  ][2], sf[2*kc  ][3]);
        u32 b0 = pk2(sf[2*kc+1][0], sf[2*kc+1][1]);
        u32 b1 = pk2(sf[2*kc+1][2], sf[2*kc+1][3]);
        asm("v_permlane32_swap_b32 %0, %1" : "+v"(a0), "+v"(b0));
        asm("v_permlane16_swap_b32 %0, %1" : "+v"(a0), "+v"(b0));  // a0=T0, b0=T2
        asm("v_permlane32_swap_b32 %0, %1" : "+v"(a1), "+v"(b1));
        asm("v_permlane16_swap_b32 %0, %1" : "+v"(a1), "+v"(b1));  // a1=T1, b1=T3
        bf16x8 pf;
        ((u32*)&pf)[0]=a0; ((u32*)&pf)[1]=a1; ((u32*)&pf)[2]=b0; ((u32*)&pf)[3]=b1;
        int kcg = ph*8 + kc;
        bf16x8 v0 = *(const bf16x8*)&lV[(size_t)((kcg*2+0)*64 + lane)*8];
        bf16x8 v1 = *(const bf16x8*)&lV[(size_t)((kcg*2+1)*64 + lane)*8];
        __builtin_amdgcn_s_setprio(1);
        o0 = __builtin_amdgcn_mfma_f32_16x16x32_bf16(pf, v0, o0, 0,0,0);
        o1 = __builtin_amdgcn_mfma_f32_16x16x32_bf16(pf, v1, o1, 0,0,0);
        __builtin_amdgcn_s_setprio(0);
      }
    }
    #pragma unroll
    for (int v=0;v<4;v++){
      float inv = 1.0f / __shfl(s, lg*4+v);
      int n = r0 + lg*4 + v;
      size_t base = ((size_t)bid*512 + n)*32;
      outF[base + lr]      = f2b(o0[v]*inv);
      outF[base + 16 + lr] = f2b(o1[v]*inv);
    }
  }
}

// ---------------- host launch ----------------
extern "C" void kernel_launch(void* const* d_in, const int* in_sizes, int n_in,
                              void* d_out, int out_size, void* d_ws, size_t ws_size,
                              hipStream_t stream){
  const float* x      = (const float*)d_in[0];
  const float* y      = (const float*)d_in[1];
  const float* n1_g   = (const float*)d_in[2];
  const float* n1_b   = (const float*)d_in[3];
  const float* qkv_w  = (const float*)d_in[4];
  const float* qkv_b  = (const float*)d_in[5];
  const float* pp_w   = (const float*)d_in[6];
  const float* pp_b   = (const float*)d_in[7];
  const float* p1_lng = (const float*)d_in[8];
  const float* p1_lnb = (const float*)d_in[9];
  const float* p1_w   = (const float*)d_in[10];
  const float* p1_b   = (const float*)d_in[11];
  const float* p2_lng = (const float*)d_in[12];
  const float* p2_lnb = (const float*)d_in[13];
  const float* p2_w   = (const float*)d_in[14];
  const float* p2_b   = (const float*)d_in[15];
  const float* p3_lng = (const float*)d_in[16];
  const float* p3_lnb = (const float*)d_in[17];
  const float* p3_w   = (const float*)d_in[18];
  const float* p3_b   = (const float*)d_in[19];
  const float* proj_w = (const float*)d_in[20];
  const float* proj_b = (const float*)d_in[21];
  const float* n2_g   = (const float*)d_in[22];
  const float* n2_b   = (const float*)d_in[23];
  const float* fc1_w  = (const float*)d_in[24];
  const float* fc1_b  = (const float*)d_in[25];
  const float* fc2_w  = (const float*)d_in[26];
  const float* fc2_b  = (const float*)d_in[27];
  float* out = (float*)d_out;
  char* ws = (char*)d_ws;

  // workspace layout (bytes)
  u16*   qkvT  = (u16*)  (ws + 0);          // [768][256] bf16
  u16*   projT = (u16*)  (ws + 393216);     // [256][256]
  u16*   fc1T  = (u16*)  (ws + 524288);     // [1024][256]
  u16*   fc2T  = (u16*)  (ws + 1048576);    // [256][1024]
  u16*   posb  = (u16*)  (ws + 1572864);    // [8][3376] bf16 per-head pos tables (x log2e)
  u16*   xn    = (u16*)  (ws + 5898240);    // [32768][256]
  u16*   yb    = (u16*)  (ws + 22675456);
  u16*   Qb    = (u16*)  (ws + 39452672);   // [512 bh][512 n][32 d]
  u16*   Kfb   = (u16*)  (ws + 56229888);   // [512 bh][32 frag][64 lane][8]
  u16*   Vfb   = (u16*)  (ws + 73007104);   // [512 bh][32 frag][64 lane][8]
  u16*   attnF = (u16*)  (ws + 89784320);   // [512 bh][512 n][32 d] block-contiguous
  float* xres  = (float*)(ws + 106561536);  // [32768][256] fp32   (end 140,115,968)
  u16*   hbuf  = xn;     // alias: MLP hidden [32768][1024], xn/yb/Qb/Kfb dead by then
  u16*   x2n   = attnF;  // alias: LN2 output, attnF dead after proj

  wtrall_k<<<3072,256,0,stream>>>(qkv_w, proj_w, fc1_w, fc2_w, qkvT, projT, fc1T, fc2T);
  posmlp_k<<<14,256,0,stream>>>(pp_w, pp_b,
                                p1_lng,p1_lnb,p1_w,p1_b,
                                p2_lng,p2_lnb,p2_w,p2_b,
                                p3_lng,p3_lnb,p3_w,p3_b, posb);
  ln_k<<<8192,256,0,stream>>>(x, n1_g, n1_b, xn);
  conv_k<<<2048,256,0,stream>>>(y, yb, 2097152);

  GemmP pq; pq.A=xn; pq.Bt=qkvT; pq.K=256; pq.bvec=qkv_b;
  pq.scale=0.17677669529663687f*1.4426950408889634f;  // hd^-0.5 * log2(e)
  pq.add32=nullptr; pq.out32=nullptr; pq.out16=Qb; pq.out16b=nullptr;
  gemm256_k<0><<<dim3(2,256),512,0,stream>>>(pq);

  GemmP pkv; pkv.A=yb; pkv.Bt=qkvT + 256*256; pkv.K=256; pkv.bvec=qkv_b + 256;
  pkv.scale=1.f; pkv.add32=nullptr; pkv.out32=nullptr; pkv.out16=Kfb; pkv.out16b=Vfb;
  gemm256_k<1><<<dim3(4,256),512,0,stream>>>(pkv);

  attn_k<<<512,512,0,stream>>>(Qb, Kfb, Vfb, posb, attnF);

  GemmP pp; pp.A=attnF; pp.Bt=projT; pp.K=256; pp.bvec=proj_b;
  pp.scale=1.f; pp.add32=x; pp.out32=xres; pp.out16=nullptr; pp.out16b=nullptr;
  gemm256_k<2><<<dim3(2,256),512,0,stream>>>(pp);

  ln_k<<<8192,256,0,stream>>>(xres, n2_g, n2_b, x2n);

  GemmP pf1; pf1.A=x2n; pf1.Bt=fc1T; pf1.K=256; pf1.bvec=fc1_b;
  pf1.scale=1.f; pf1.add32=nullptr; pf1.out32=nullptr; pf1.out16=hbuf; pf1.out16b=nullptr;
  gemm256_k<3><<<dim3(8,256),512,0,stream>>>(pf1);

  GemmP pf2; pf2.A=hbuf; pf2.Bt=fc2T; pf2.K=1024; pf2.bvec=fc2_b;
  pf2.scale=1.f; pf2.add32=xres; pf2.out32=out; pf2.out16=nullptr; pf2.out16b=nullptr;
  gemm_k<4><<<dim3(2,256),256,0,stream>>>(pf2);
}

// Round 7
// 282.388 us; speedup vs baseline: 1.4547x; 1.0326x over previous
//
#include <hip/hip_runtime.h>
#include <cstdint>
#include <cstddef>

typedef unsigned int u32;
typedef unsigned short u16;
typedef __attribute__((ext_vector_type(8))) short bf16x8;   // 8 bf16 = 4 VGPR
typedef __attribute__((ext_vector_type(4))) float f32x4;

#define DEV __device__ __forceinline__

DEV float b2f(u16 u){ return __uint_as_float(((u32)u)<<16); }
DEV u16 f2b(float f){ u32 x = __float_as_uint(f); x += 0x7fffu + ((x>>16)&1u); return (u16)(x>>16); }
DEV u32 pk2(float a, float b){
  u32 r;
  asm("v_cvt_pk_bf16_f32 %0, %1, %2" : "=v"(r) : "v"(a), "v"(b));
  return r;
}

DEV void gll16(const void* g, void* l){
  __builtin_amdgcn_global_load_lds((const __attribute__((address_space(1))) u32*)g,
                                   (__attribute__((address_space(3))) u32*)l, 16, 0, 0);
}

// token row -> (window, in-window index);  H=W=D=32, g=8
DEV void win_n(int r, int& win, int& n){
  int d_ = r & 31, w_ = (r>>5)&31, h_ = r>>10;
  win = ((h_>>3)<<4) | ((w_>>3)<<2) | (d_>>3);
  n   = ((h_&7)<<6)  | ((w_&7)<<3)  | (d_&7);
}
// window-order row -> token row
DEV int tok_of(int r){
  int win = r>>9, nn = r&511;
  int bh = win>>4, bw=(win>>2)&3, bd=win&3;
  int ih = nn>>6,  iw=(nn>>3)&7,  id=nn&7;
  return ((bh*8+ih)<<10) | ((bw*8+iw)<<5) | (bd*8+id);
}

// ---------------- small prep kernels ----------------

// all four weight transposes in one dispatch: dst bf16 [N][K] = transpose(src fp32 [K][N])
__global__ void wtrall_k(const float* __restrict__ qkv_w, const float* __restrict__ proj_w,
                         const float* __restrict__ fc1_w, const float* __restrict__ fc2_w,
                         u16* __restrict__ qkvT, u16* __restrict__ projT,
                         u16* __restrict__ fc1T, u16* __restrict__ fc2T){
  int f = blockIdx.x*256 + threadIdx.x;   // 786432 total
  const float* w; u16* wt; int g; bool k10 = false; int N;
  if (f < 196608)      { w=qkv_w;  wt=qkvT;  g=f;        N=768;  }
  else if (f < 262144) { w=proj_w; wt=projT; g=f-196608; N=256;  }
  else if (f < 524288) { w=fc1_w;  wt=fc1T;  g=f-262144; N=1024; }
  else                 { w=fc2_w;  wt=fc2T;  g=f-524288; N=256;  k10=true; }
  int n = k10 ? (g>>10) : (g>>8);
  int k = k10 ? (g&1023) : (g&255);
  wt[g] = f2b(w[(size_t)k*N + n]);
}

__global__ void conv_k(const float* __restrict__ x, u16* __restrict__ o, int n4){
  int stride = gridDim.x*blockDim.x;
  for (int i = blockIdx.x*blockDim.x + threadIdx.x; i < n4; i += stride){
    const float4 v = *(const float4*)(x + (size_t)i*4);
    u32 lo = (u32)f2b(v.x) | ((u32)f2b(v.y)<<16);
    u32 hi = (u32)f2b(v.z) | ((u32)f2b(v.w)<<16);
    *(uint2*)(o + (size_t)i*4) = make_uint2(lo, hi);
  }
}

// LayerNorm over 256 cols, one wave per row, writes bf16
__global__ __launch_bounds__(256)
void ln_k(const float* __restrict__ x, const float* __restrict__ g,
          const float* __restrict__ b, u16* __restrict__ out){
  int row  = blockIdx.x*4 + (threadIdx.x>>6);
  int lane = threadIdx.x & 63;
  const float4 v = *(const float4*)(x + (size_t)row*256 + lane*4);
  float s = v.x+v.y+v.z+v.w;
  #pragma unroll
  for (int m=1;m<64;m<<=1) s += __shfl_xor(s, m);
  float mean = s * (1.0f/256.0f);
  float d0=v.x-mean,d1=v.y-mean,d2=v.z-mean,d3=v.w-mean;
  float q = d0*d0+d1*d1+d2*d2+d3*d3;
  #pragma unroll
  for (int m=1;m<64;m<<=1) q += __shfl_xor(q, m);
  float rs = rsqrtf(q*(1.0f/256.0f) + 1e-5f);
  const float4 gg = *(const float4*)(g + lane*4);
  const float4 bb = *(const float4*)(b + lane*4);
  u32 lo = (u32)f2b(d0*rs*gg.x+bb.x) | ((u32)f2b(d1*rs*gg.y+bb.y)<<16);
  u32 hi = (u32)f2b(d2*rs*gg.z+bb.z) | ((u32)f2b(d3*rs*gg.w+bb.w)<<16);
  *(uint2*)(out + (size_t)row*256 + lane*4) = make_uint2(lo,hi);
}

// position-bias MLP: one thread per table row (3375 rows); emits f32 per-head tables
// scaled by log2(e) so attention softmax can run in exp2 domain.
template<int NOUT>
DEV void pstage(float* v, const float* g, const float* b, const float* W, const float* bb){
  float m = 0.f;
  #pragma unroll
  for (int i=0;i<16;i++) m += v[i];
  m *= 0.0625f;
  float q = 0.f;
  #pragma unroll
  for (int i=0;i<16;i++){ float d=v[i]-m; q += d*d; }
  float rs = rsqrtf(q*0.0625f + 1e-5f);
  float u[16];
  #pragma unroll
  for (int i=0;i<16;i++){ float t = (v[i]-m)*rs*g[i] + b[i]; u[i] = t>0.f?t:0.f; }
  #pragma unroll
  for (int o=0;o<NOUT;o++){
    float s = bb[o];
    #pragma unroll
    for (int kk=0;kk<16;kk++) s += u[kk]*W[kk*NOUT+o];
    v[o] = s;
  }
}

__global__ void posmlp_k(const float* pp_w, const float* pp_b,
                         const float* g1, const float* b1, const float* w1, const float* bb1,
                         const float* g2, const float* b2, const float* w2, const float* bb2,
                         const float* g3, const float* b3, const float* w3, const float* bb3,
                         float* __restrict__ posb){
  int i = blockIdx.x*256 + threadIdx.x;
  if (i >= 3375) return;
  int t = i;
  int bd = t % 15; t /= 15;
  int bw = t % 15; t /= 15;
  int bh = t;
  float fh = (float)(bh-7), fw = (float)(bw-7), fd = (float)(bd-7);
  float v[16];
  #pragma unroll
  for (int o=0;o<16;o++) v[o] = fh*pp_w[o] + fw*pp_w[16+o] + fd*pp_w[32+o] + pp_b[o];
  pstage<16>(v, g1,b1,w1,bb1);
  pstage<16>(v, g2,b2,w2,bb2);
  pstage<8> (v, g3,b3,w3,bb3);
  #pragma unroll
  for (int h=0;h<8;h++) posb[(size_t)h*3376 + i] = v[h] * 1.4426950408889634f;
}

// ---------------- GEMM params ----------------
struct GemmP {
  const u16* A; const u16* Bt;
  int K;
  const float* bvec;
  float scale;
  const float* add32;
  float* out32;
  u16* out16;
  u16* out16b;
};

// shared epilogue: D layout col=lane&15, row=(lane>>4)*4+v  [verified m89]
template<int MODE>
DEV void epi(const GemmP& p, int r, int c, float val){
  if constexpr (MODE==0){           // Q: (val+b)*scale -> Q[win*8+h][n][d]
    float qv = (val + p.bvec[c]) * p.scale;
    int win, n; win_n(r, win, n);
    int hh = c>>5, dd = c&31;
    p.out16[((size_t)((win*8+hh)*512 + n)<<5) + dd] = f2b(qv);
  } else if constexpr (MODE==1){    // K (c<256) / V (c>=256), MFMA fragment layout
    float ov = val + p.bvec[c];
    int win, n; win_n(r, win, n);
    int cc = c & 255;
    int hh = cc>>5, dd = cc&31;
    size_t base = (size_t)(win*8+hh)*16384;
    if (c < 256){
      int nc = n>>4, ln2 = ((dd>>3)<<4)|(n&15), jj = dd&7;
      p.out16[base + (size_t)(nc*64+ln2)*8 + jj] = f2b(ov);
    } else {
      int fi = ((n>>5)<<1) | (dd>>4);
      int ln2 = (((n>>3)&3)<<4)|(dd&15), jj = n&7;
      p.out16b[base + (size_t)(fi*64+ln2)*8 + jj] = f2b(ov);
    }
  } else if constexpr (MODE==2){    // proj + x residual, window row -> token row
    int l = tok_of(r);
    size_t o = (size_t)l*256 + c;
    p.out32[o] = val + p.bvec[c] + p.add32[o];
  } else if constexpr (MODE==3){    // fc1 + exact GELU
    float u = val + p.bvec[c];
    float ge = 0.5f*u*(1.0f + erff(u*0.70710678118654752f));
    p.out16[(size_t)r*1024 + c] = f2b(ge);
  } else {                          // fc2 + residual -> fp32 out
    size_t o = (size_t)r*256 + c;
    p.out32[o] = val + p.bvec[c] + p.add32[o];
  }
}

// ---------------- GEMM: T4 counted-vmcnt double-buffered pipeline ----------------
// 128x128 tile, 256 threads (4 waves 2x2), BK=32, LDS 32KB.
// Per K-tile: issue next-tile gll16 -> s_waitcnt vmcnt(4) (never 0 mid-loop) ->
// s_barrier -> ds_read+16 MFMA -> sched_barrier -> s_barrier. Prefetch stays in
// flight across barriers (removes the __syncthreads vmcnt(0) drain = m97 ceiling).
// grid: x = n-block (fast), y = m-block -> consecutive blocks share A panel (L2-hot).
template<int MODE>
__global__ __launch_bounds__(256)
void gemm_k(GemmP p){
  __shared__ u16 lA[2][4096];
  __shared__ u16 lB[2][4096];
  const int tid = threadIdx.x;
  const int wid = tid>>6, lane = tid&63;
  const int lr = lane&15, lg = lane>>4;
  const int m0 = blockIdx.y*128, n0 = blockIdx.x*128;
  const int K = p.K;
  const int nt = K>>5;
  const int wm = (wid>>1)*64, wn = (wid&1)*64;
  const f32x4 z4 = {0.f,0.f,0.f,0.f};

  auto stage = [&](int buf, int t){
    #pragma unroll
    for (int r=0;r<2;r++){
      int off = (r*256 + tid)*16;
      int row = off>>6, kc = (off&63)>>1;
      int kcol = (t<<5) + kc;
      const u16* ga;
      if constexpr (MODE==2){
        int rr = m0 + row;               // A = attnF [win*8+h][512 n][32 d]
        ga = p.A + ((size_t)((rr>>9)*8 + (kcol>>5))*512 + (rr&511))*32 + (kcol&31);
      } else {
        ga = p.A + (size_t)(m0+row)*K + kcol;
      }
      gll16(ga, (char*)lA[buf] + off);
      gll16(p.Bt + (size_t)(n0+row)*K + kcol, (char*)lB[buf] + off);
    }
  };

  f32x4 acc[4][4];
  #pragma unroll
  for (int i=0;i<4;i++)
    #pragma unroll
    for (int j=0;j<4;j++) acc[i][j] = z4;

  stage(0, 0);
  int cur = 0;
  for (int t=0; t<nt; ++t){
    if (t+1 < nt){
      stage(cur^1, t+1);
      asm volatile("s_waitcnt vmcnt(4)" ::: "memory");   // tile-t loads landed (mine)
    } else {
      asm volatile("s_waitcnt vmcnt(0)" ::: "memory");
    }
    __builtin_amdgcn_s_barrier();                        // everyone's tile-t loads landed
    __builtin_amdgcn_sched_barrier(0);
    bf16x8 af[4], bfr[4];
    #pragma unroll
    for (int i=0;i<4;i++){
      af[i]  = *(const bf16x8*)&lA[cur][(wm + i*16 + lr)*32 + lg*8];
      bfr[i] = *(const bf16x8*)&lB[cur][(wn + i*16 + lr)*32 + lg*8];
    }
    #pragma unroll
    for (int i=0;i<4;i++)
      #pragma unroll
      for (int j=0;j<4;j++)
        acc[i][j] = __builtin_amdgcn_mfma_f32_16x16x32_bf16(af[i], bfr[j], acc[i][j], 0,0,0);
    if (t+1 < nt){
      __builtin_amdgcn_sched_barrier(0);                 // pin ds_reads above
      __builtin_amdgcn_s_barrier();                      // reads done before next overwrite
    }
    cur ^= 1;
  }

  #pragma unroll
  for (int i=0;i<4;i++)
    #pragma unroll
    for (int j=0;j<4;j++)
      #pragma unroll
      for (int v=0;v<4;v++)
        epi<MODE>(p, m0 + wm + i*16 + lg*4 + v, n0 + wn + j*16 + lr, acc[i][j][v]);
}

// ---------------- attention: one block per (window, head), 8 waves, flash 2-phase ----------------
// exp2-domain softmax; defer-rescale (T13); setprio (T5); bias from f32 LDS table
// (4 consecutive f32 per fragment -> 2x ds_read2_b32, no unpack VALU).
__global__ __launch_bounds__(512, 2)
void attn_k(const u16* __restrict__ Q, const u16* __restrict__ Kf,
            const u16* __restrict__ Vf, const float* __restrict__ posb,
            u16* __restrict__ outF){
  __shared__ u16 lK[16384];      // 32 frags x 1KB, fragment order
  __shared__ u16 lV[16384];      // 32 frags x 1KB (16 kc x 2 dblk)
  __shared__ float lPf[3392];    // pos table f32 (x log2e)
  const int bid = blockIdx.x;
  const int hh = bid&7;
  const int tid = threadIdx.x, wid = tid>>6, lane = tid&63;
  const int lr = lane&15, lg = lane>>4;
  const u16* Kb = Kf + (size_t)bid*16384;
  const u16* Vb = Vf + (size_t)bid*16384;
  const u16* Qb = Q  + (size_t)bid*16384;
  #pragma unroll
  for (int r=0;r<4;r++){
    int off = (r*512 + tid)*16;
    gll16((const char*)Kb + off, (char*)lK + off);
    gll16((const char*)Vb + off, (char*)lV + off);
  }
  const float* ptab = posb + (size_t)hh*3376;
  for (int t=tid; t<3375; t+=512) lPf[t] = ptab[t];
  __syncthreads();
  const f32x4 z4 = {0.f,0.f,0.f,0.f};

  for (int ch=0; ch<4; ++ch){
    const int r0 = wid*64 + ch*16;
    const int q  = r0 + lr;
    // bias index base: idx(nc,v) = Ab - (nc>>2)*225 - (nc&3)*30 - v
    const int Ab = (q>>6)*225 + ((q>>3)&7)*15 + (q&7) + 1687 - (lg>>1)*15 - (lg&1)*4;
    bf16x8 qf = *(const bf16x8*)(Qb + (size_t)q*32 + lg*8);
    f32x4 o0 = z4, o1 = z4;
    float m = -3.0e38f, s = 0.f;
    #pragma unroll
    for (int ph=0; ph<2; ++ph){
      // S^T frags for this half: sf[i][v] = S[q][n=(ph*16+i)*16+lg*4+v]  (exp2 domain)
      f32x4 sf[16];
      __builtin_amdgcn_s_setprio(1);
      #pragma unroll
      for (int i=0;i<16;i++){
        int nc = ph*16 + i;
        bf16x8 kf = *(const bf16x8*)&lK[(nc*64 + lane)*8];
        sf[i] = __builtin_amdgcn_mfma_f32_16x16x32_bf16(kf, qf, z4, 0,0,0);
      }
      __builtin_amdgcn_s_setprio(0);
      // + bias: 4 consecutive f32 from LDS (compiler fuses into ds_read2_b32 pairs)
      #pragma unroll
      for (int i=0;i<16;i++){
        int nc = ph*16 + i;
        const float* bp = lPf + (Ab - (nc>>2)*225 - (nc&3)*30 - 3);
        sf[i][3] += bp[0];
        sf[i][2] += bp[1];
        sf[i][1] += bp[2];
        sf[i][0] += bp[3];
      }
      // row max of this half (row q per lane; combine lg groups)
      float pm = -3.0e38f;
      #pragma unroll
      for (int i=0;i<16;i++)
        pm = fmaxf(pm, fmaxf(fmaxf(sf[i][0],sf[i][1]), fmaxf(sf[i][2],sf[i][3])));
      pm = fmaxf(pm, __shfl_xor(pm,16));
      pm = fmaxf(pm, __shfl_xor(pm,32));
      if (ph == 0){
        m = pm;
      } else if (!__all(pm <= m + 8.0f)){  // T13: skip rescale when max barely grew
        float mn = fmaxf(m, pm);
        float f = exp2f(m - mn);
        s *= f;
        float f0 = __shfl(f, lg*4+0), f1 = __shfl(f, lg*4+1);
        float f2 = __shfl(f, lg*4+2), f3 = __shfl(f, lg*4+3);
        o0[0]*=f0; o0[1]*=f1; o0[2]*=f2; o0[3]*=f3;
        o1[0]*=f0; o1[1]*=f1; o1[2]*=f2; o1[3]*=f3;
        m = mn;
      }
      float ls = 0.f;
      #pragma unroll
      for (int i=0;i<16;i++){
        #pragma unroll
        for (int v=0;v<4;v++){ float e = exp2f(sf[i][v]-m); sf[i][v]=e; ls+=e; }
      }
      ls += __shfl_xor(ls,16);
      ls += __shfl_xor(ls,32);
      s += ls;
      // PV over this half's 8 kc blocks
      #pragma unroll
      for (int kc=0;kc<8;kc++){
        u32 a0 = pk2(sf[2*kc  ][0], sf[2*kc  ][1]);
        u32 a1 = pk2(sf[2*kc  ][2], sf[2*kc  ][3]);
        u32 b0 = pk2(sf[2*kc+1][0], sf[2*kc+1][1]);
        u32 b1 = pk2(sf[2*kc+1][2], sf[2*kc+1][3]);
        asm("v_permlane32_swap_b32 %0, %1" : "+v"(a0), "+v"(b0));
        asm("v_permlane16_swap_b32 %0, %1" : "+v"(a0), "+v"(b0));  // a0=T0, b0=T2
        asm("v_permlane32_swap_b32 %0, %1" : "+v"(a1), "+v"(b1));
        asm("v_permlane16_swap_b32 %0, %1" : "+v"(a1), "+v"(b1));  // a1=T1, b1=T3
        bf16x8 pf;
        ((u32*)&pf)[0]=a0; ((u32*)&pf)[1]=a1; ((u32*)&pf)[2]=b0; ((u32*)&pf)[3]=b1;
        int kcg = ph*8 + kc;
        bf16x8 v0 = *(const bf16x8*)&lV[(size_t)((kcg*2+0)*64 + lane)*8];
        bf16x8 v1 = *(const bf16x8*)&lV[(size_t)((kcg*2+1)*64 + lane)*8];
        __builtin_amdgcn_s_setprio(1);
        o0 = __builtin_amdgcn_mfma_f32_16x16x32_bf16(pf, v0, o0, 0,0,0);
        o1 = __builtin_amdgcn_mfma_f32_16x16x32_bf16(pf, v1, o1, 0,0,0);
        __builtin_amdgcn_s_setprio(0);
      }
    }
    #pragma unroll
    for (int v=0;v<4;v++){
      float inv = 1.0f / __shfl(s, lg*4+v);
      int n = r0 + lg*4 + v;
      size_t base = ((size_t)bid*512 + n)*32;
      outF[base + lr]      = f2b(o0[v]*inv);
      outF[base + 16 + lr] = f2b(o1[v]*inv);
    }
  }
}

// ---------------- host launch ----------------
extern "C" void kernel_launch(void* const* d_in, const int* in_sizes, int n_in,
                              void* d_out, int out_size, void* d_ws, size_t ws_size,
                              hipStream_t stream){
  const float* x      = (const float*)d_in[0];
  const float* y      = (const float*)d_in[1];
  const float* n1_g   = (const float*)d_in[2];
  const float* n1_b   = (const float*)d_in[3];
  const float* qkv_w  = (const float*)d_in[4];
  const float* qkv_b  = (const float*)d_in[5];
  const float* pp_w   = (const float*)d_in[6];
  const float* pp_b   = (const float*)d_in[7];
  const float* p1_lng = (const float*)d_in[8];
  const float* p1_lnb = (const float*)d_in[9];
  const float* p1_w   = (const float*)d_in[10];
  const float* p1_b   = (const float*)d_in[11];
  const float* p2_lng = (const float*)d_in[12];
  const float* p2_lnb = (const float*)d_in[13];
  const float* p2_w   = (const float*)d_in[14];
  const float* p2_b   = (const float*)d_in[15];
  const float* p3_lng = (const float*)d_in[16];
  const float* p3_lnb = (const float*)d_in[17];
  const float* p3_w   = (const float*)d_in[18];
  const float* p3_b   = (const float*)d_in[19];
  const float* proj_w = (const float*)d_in[20];
  const float* proj_b = (const float*)d_in[21];
  const float* n2_g   = (const float*)d_in[22];
  const float* n2_b   = (const float*)d_in[23];
  const float* fc1_w  = (const float*)d_in[24];
  const float* fc1_b  = (const float*)d_in[25];
  const float* fc2_w  = (const float*)d_in[26];
  const float* fc2_b  = (const float*)d_in[27];
  float* out = (float*)d_out;
  char* ws = (char*)d_ws;

  // workspace layout (bytes)
  u16*   qkvT  = (u16*)  (ws + 0);          // [768][256] bf16
  u16*   projT = (u16*)  (ws + 393216);     // [256][256]
  u16*   fc1T  = (u16*)  (ws + 524288);     // [1024][256]
  u16*   fc2T  = (u16*)  (ws + 1048576);    // [256][1024]
  float* posb  = (float*)(ws + 1572864);    // [8][3376] f32 per-head pos tables (x log2e)
  u16*   xn    = (u16*)  (ws + 5898240);    // [32768][256]
  u16*   yb    = (u16*)  (ws + 22675456);
  u16*   Qb    = (u16*)  (ws + 39452672);   // [512 bh][512 n][32 d]
  u16*   Kfb   = (u16*)  (ws + 56229888);   // [512 bh][32 frag][64 lane][8]
  u16*   Vfb   = (u16*)  (ws + 73007104);   // [512 bh][32 frag][64 lane][8]
  u16*   attnF = (u16*)  (ws + 89784320);   // [512 bh][512 n][32 d] block-contiguous
  float* xres  = (float*)(ws + 106561536);  // [32768][256] fp32   (end 140,115,968)
  u16*   hbuf  = xn;     // alias: MLP hidden [32768][1024], xn/yb/Qb/Kfb dead by then
  u16*   x2n   = attnF;  // alias: LN2 output, attnF dead after proj

  wtrall_k<<<3072,256,0,stream>>>(qkv_w, proj_w, fc1_w, fc2_w, qkvT, projT, fc1T, fc2T);
  posmlp_k<<<14,256,0,stream>>>(pp_w, pp_b,
                                p1_lng,p1_lnb,p1_w,p1_b,
                                p2_lng,p2_lnb,p2_w,p2_b,
                                p3_lng,p3_lnb,p3_w,p3_b, posb);
  ln_k<<<8192,256,0,stream>>>(x, n1_g, n1_b, xn);
  conv_k<<<2048,256,0,stream>>>(y, yb, 2097152);

  GemmP pq; pq.A=xn; pq.Bt=qkvT; pq.K=256; pq.bvec=qkv_b;
  pq.scale=0.17677669529663687f*1.4426950408889634f;  // hd^-0.5 * log2(e)
  pq.add32=nullptr; pq.out32=nullptr; pq.out16=Qb; pq.out16b=nullptr;
  gemm_k<0><<<dim3(2,256),256,0,stream>>>(pq);

  GemmP pkv; pkv.A=yb; pkv.Bt=qkvT + 256*256; pkv.K=256; pkv.bvec=qkv_b + 256;
  pkv.scale=1.f; pkv.add32=nullptr; pkv.out32=nullptr; pkv.out16=Kfb; pkv.out16b=Vfb;
  gemm_k<1><<<dim3(4,256),256,0,stream>>>(pkv);

  attn_k<<<512,512,0,stream>>>(Qb, Kfb, Vfb, posb, attnF);

  GemmP pp; pp.A=attnF; pp.Bt=projT; pp.K=256; pp.bvec=proj_b;
  pp.scale=1.f; pp.add32=x; pp.out32=xres; pp.out16=nullptr; pp.out16b=nullptr;
  gemm_k<2><<<dim3(2,256),256,0,stream>>>(pp);

  ln_k<<<8192,256,0,stream>>>(xres, n2_g, n2_b, x2n);

  GemmP pf1; pf1.A=x2n; pf1.Bt=fc1T; pf1.K=256; pf1.bvec=fc1_b;
  pf1.scale=1.f; pf1.add32=nullptr; pf1.out32=nullptr; pf1.out16=hbuf; pf1.out16b=nullptr;
  gemm_k<3><<<dim3(8,256),256,0,stream>>>(pf1);

  GemmP pf2; pf2.A=hbuf; pf2.Bt=fc2T; pf2.K=1024; pf2.bvec=fc2_b;
  pf2.scale=1.f; pf2.add32=xres; pf2.out32=out; pf2.out16=nullptr; pf2.out16b=nullptr;
  gemm_k<4><<<dim3(2,256),256,0,stream>>>(pf2);
}